// Round 1
// baseline (902.482 us; speedup 1.0000x reference)
//
#include <hip/hip_runtime.h>
#include <math.h>

#define NEG_SLOPE 0.2f

// ---------------- CSR build ----------------

__global__ __launch_bounds__(256) void k_count(const int* __restrict__ ei, int E, int Et,
                                               int* __restrict__ cnt) {
    int e = blockIdx.x * 256 + threadIdx.x;
    if (e < Et) {
        int d = (e < E) ? ei[E + e] : (e - E);   // self-loop edges at the tail
        atomicAdd(&cnt[d], 1);
    }
}

__global__ __launch_bounds__(256) void k_scan_block(const int* __restrict__ cnt,
                                                    int* __restrict__ out,
                                                    int* __restrict__ bsums, int n) {
    __shared__ int tmp[256];
    int t = threadIdx.x;
    int i = blockIdx.x * 256 + t;
    int v = (i < n) ? cnt[i] : 0;
    tmp[t] = v;
    __syncthreads();
    for (int d = 1; d < 256; d <<= 1) {
        int add = (t >= d) ? tmp[t - d] : 0;
        __syncthreads();
        tmp[t] += add;
        __syncthreads();
    }
    if (i < n) out[i] = tmp[t] - v;              // exclusive scan within block
    if (t == 255) bsums[blockIdx.x] = tmp[t];    // block total
}

__global__ __launch_bounds__(256) void k_scan_bsums(int* bsums, int nb) {
    __shared__ int tmp[256];
    int t = threadIdx.x;
    int v = (t < nb) ? bsums[t] : 0;
    tmp[t] = v;
    __syncthreads();
    for (int d = 1; d < 256; d <<= 1) {
        int add = (t >= d) ? tmp[t - d] : 0;
        __syncthreads();
        tmp[t] += add;
        __syncthreads();
    }
    if (t < nb) bsums[t] = tmp[t] - v;           // exclusive block offsets
}

__global__ __launch_bounds__(256) void k_scan_add(int* __restrict__ out,
                                                  const int* __restrict__ bsums,
                                                  int n, int total) {
    int i = blockIdx.x * 256 + threadIdx.x;
    if (i < n) out[i] += bsums[blockIdx.x];
    if (i == 0) out[n] = total;                  // row_ptr[N] = Et
}

__global__ __launch_bounds__(256) void k_cursor_init(const int* __restrict__ row_ptr,
                                                     int* __restrict__ cursor, int n) {
    int i = blockIdx.x * 256 + threadIdx.x;
    if (i < n) cursor[i] = row_ptr[i];
}

__global__ __launch_bounds__(256) void k_scatter(const int* __restrict__ ei, int E, int Et,
                                                 int* __restrict__ cursor,
                                                 int* __restrict__ src_sorted) {
    int e = blockIdx.x * 256 + threadIdx.x;
    if (e < Et) {
        int s, d;
        if (e < E) { s = ei[e]; d = ei[E + e]; } else { s = d = e - E; }
        int pos = atomicAdd(&cursor[d], 1);
        src_sorted[pos] = s;
    }
}

// ---------------- Tiled fp32 GEMM: [M,K] @ {Wl,Wr}[K,256] + bias ----------------
// 64x64 tile per block, both weight matrices share the A tile.

__global__ __launch_bounds__(256) void k_gemm_pair(const float* __restrict__ A, int M, int K,
                                                   const float* __restrict__ Wl,
                                                   const float* __restrict__ Wr,
                                                   const float* __restrict__ bl,
                                                   const float* __restrict__ br,
                                                   float* __restrict__ Cl,
                                                   float* __restrict__ Cr) {
    __shared__ float Ast[16][68];   // transposed A tile: Ast[k][m]
    __shared__ float Bls[16][68];
    __shared__ float Brs[16][68];
    const int row0 = blockIdx.x * 64;
    const int col0 = blockIdx.y * 64;
    const int t  = threadIdx.x;
    const int tx = t & 15, ty = t >> 4;
    float accl[4][4] = {{0.f}}, accr[4][4] = {{0.f}};

    for (int k0 = 0; k0 < K; k0 += 16) {
        // A tile 64x16 (transposed into LDS), 4 scalars/thread
        #pragma unroll
        for (int i = 0; i < 4; i++) {
            int idx = t + i * 256;
            int r = idx >> 4, c = idx & 15;
            int gr = row0 + r, gk = k0 + c;
            float v = (gr < M && gk < K) ? A[gr * K + gk] : 0.0f;
            Ast[c][r] = v;
        }
        // B tiles 16x64, coalesced rows
        #pragma unroll
        for (int i = 0; i < 4; i++) {
            int idx = t + i * 256;
            int r = idx >> 6, c = idx & 63;
            int gk = k0 + r;
            float vl = 0.0f, vr = 0.0f;
            if (gk < K) {
                vl = Wl[gk * 256 + col0 + c];
                vr = Wr[gk * 256 + col0 + c];
            }
            Bls[r][c] = vl;
            Brs[r][c] = vr;
        }
        __syncthreads();
        #pragma unroll
        for (int kk = 0; kk < 16; kk++) {
            float a[4], b[4], c2[4];
            #pragma unroll
            for (int i = 0; i < 4; i++) a[i]  = Ast[kk][ty * 4 + i];
            #pragma unroll
            for (int j = 0; j < 4; j++) b[j]  = Bls[kk][tx * 4 + j];
            #pragma unroll
            for (int j = 0; j < 4; j++) c2[j] = Brs[kk][tx * 4 + j];
            #pragma unroll
            for (int i = 0; i < 4; i++)
                #pragma unroll
                for (int j = 0; j < 4; j++) {
                    accl[i][j] = fmaf(a[i], b[j],  accl[i][j]);
                    accr[i][j] = fmaf(a[i], c2[j], accr[i][j]);
                }
        }
        __syncthreads();
    }
    #pragma unroll
    for (int i = 0; i < 4; i++) {
        int gr = row0 + ty * 4 + i;
        if (gr < M) {
            #pragma unroll
            for (int j = 0; j < 4; j++) {
                int gc = col0 + tx * 4 + j;
                Cl[gr * 256 + gc] = accl[i][j] + bl[gc];
                Cr[gr * 256 + gc] = accr[i][j] + br[gc];
            }
        }
    }
}

// ---------------- Aggregation for layers 1&2 (H=4, C=64), online softmax ----------------
// one block per destination node; wave w = head, lane = channel; ELU+bias fused.

__global__ __launch_bounds__(256) void k_agg256(const float* __restrict__ xl,
                                                const float* __restrict__ xr,
                                                const int* __restrict__ row_ptr,
                                                const int* __restrict__ src_sorted,
                                                const float* __restrict__ att,
                                                const float* __restrict__ bias,
                                                float* __restrict__ h_out) {
    const int n = blockIdx.x;
    const int t = threadIdx.x;
    const float att_v  = att[t];          // [4,64] flat == t
    const float xr_v   = xr[n * 256 + t];
    const float bias_v = bias[t];

    float m = -INFINITY, s = 0.0f, acc = 0.0f;
    const int beg = row_ptr[n], end = row_ptr[n + 1];
    __shared__ int s_src[256];

    for (int base = beg; base < end; base += 256) {
        int cnt = min(256, end - base);
        if (t < cnt) s_src[t] = src_sorted[base + t];
        __syncthreads();
        for (int j = 0; j < cnt; j++) {
            int sv = s_src[j];
            float xlv = xl[sv * 256 + t];
            float tt = xlv + xr_v;
            float lr = tt > 0.0f ? tt : NEG_SLOPE * tt;
            float logit = att_v * lr;
            #pragma unroll
            for (int d = 1; d < 64; d <<= 1) logit += __shfl_xor(logit, d, 64);
            float nm = fmaxf(m, logit);
            float sc = __expf(m - nm);
            float p  = __expf(logit - nm);
            acc = acc * sc + p * xlv;
            s   = s * sc + p;
            m   = nm;
        }
        __syncthreads();
    }
    float o = acc / s + bias_v;
    h_out[n * 256 + t] = o > 0.0f ? o : (__expf(o) - 1.0f);   // ELU
}

// ---------------- Layer 3: 256 -> 6 transform ----------------

__global__ __launch_bounds__(64) void k_gemm3(const float* __restrict__ h,
                                              const float* __restrict__ Wl,
                                              const float* __restrict__ Wr,
                                              const float* __restrict__ bl,
                                              const float* __restrict__ br,
                                              float* __restrict__ xl3,
                                              float* __restrict__ xr3) {
    const int n = blockIdx.x;
    const int lane = threadIdx.x;
    float hv[4];
    #pragma unroll
    for (int i = 0; i < 4; i++) hv[i] = h[n * 256 + lane + i * 64];
    #pragma unroll
    for (int j = 0; j < 6; j++) {
        float pl = 0.0f, pr = 0.0f;
        #pragma unroll
        for (int i = 0; i < 4; i++) {
            int k = lane + i * 64;
            pl = fmaf(hv[i], Wl[k * 6 + j], pl);
            pr = fmaf(hv[i], Wr[k * 6 + j], pr);
        }
        #pragma unroll
        for (int d = 1; d < 64; d <<= 1) {
            pl += __shfl_xor(pl, d, 64);
            pr += __shfl_xor(pr, d, 64);
        }
        if (lane == 0) {
            xl3[n * 6 + j] = pl + bl[j];
            xr3[n * 6 + j] = pr + br[j];
        }
    }
}

// ---------------- Layer 3 aggregation (H=6, C=1, mean over heads) ----------------

__global__ __launch_bounds__(256) void k_agg3(const float* __restrict__ xl3,
                                              const float* __restrict__ xr3,
                                              const int* __restrict__ row_ptr,
                                              const int* __restrict__ src_sorted,
                                              const float* __restrict__ att3,
                                              const float* __restrict__ bias3,
                                              float* __restrict__ out, int N) {
    int n = blockIdx.x * 256 + threadIdx.x;
    if (n >= N) return;
    float xrv[6], attv[6], m[6], s[6], acc[6];
    #pragma unroll
    for (int j = 0; j < 6; j++) {
        xrv[j] = xr3[n * 6 + j];
        attv[j] = att3[j];
        m[j] = -INFINITY; s[j] = 0.0f; acc[j] = 0.0f;
    }
    int beg = row_ptr[n], end = row_ptr[n + 1];
    for (int idx = beg; idx < end; idx++) {
        int sv = src_sorted[idx];
        #pragma unroll
        for (int j = 0; j < 6; j++) {
            float xlv = xl3[sv * 6 + j];
            float tt = xlv + xrv[j];
            float lr = tt > 0.0f ? tt : NEG_SLOPE * tt;
            float logit = attv[j] * lr;
            float nm = fmaxf(m[j], logit);
            float sc = __expf(m[j] - nm);
            float p  = __expf(logit - nm);
            acc[j] = acc[j] * sc + p * xlv;
            s[j]   = s[j] * sc + p;
            m[j]   = nm;
        }
    }
    float o = 0.0f;
    #pragma unroll
    for (int j = 0; j < 6; j++) o += acc[j] / s[j];
    out[n] = o * (1.0f / 6.0f) + bias3[0];
}

// ---------------- launch ----------------

extern "C" void kernel_launch(void* const* d_in, const int* in_sizes, int n_in,
                              void* d_out, int out_size, void* d_ws, size_t ws_size,
                              hipStream_t stream) {
    const float* x    = (const float*)d_in[0];
    const int*   ei   = (const int*)  d_in[1];
    const float* Wl1  = (const float*)d_in[2];
    const float* bl1  = (const float*)d_in[3];
    const float* Wr1  = (const float*)d_in[4];
    const float* br1  = (const float*)d_in[5];
    const float* att1 = (const float*)d_in[6];
    const float* bias1= (const float*)d_in[7];
    const float* Wl2  = (const float*)d_in[8];
    const float* bl2  = (const float*)d_in[9];
    const float* Wr2  = (const float*)d_in[10];
    const float* br2  = (const float*)d_in[11];
    const float* att2 = (const float*)d_in[12];
    const float* bias2= (const float*)d_in[13];
    const float* Wl3  = (const float*)d_in[14];
    const float* bl3  = (const float*)d_in[15];
    const float* Wr3  = (const float*)d_in[16];
    const float* br3  = (const float*)d_in[17];
    const float* att3 = (const float*)d_in[18];
    const float* bias3= (const float*)d_in[19];

    const int F  = in_sizes[2] / 256;   // 58
    const int N  = in_sizes[0] / F;     // 50000
    const int E  = in_sizes[1] / 2;     // 500000
    const int Et = E + N;

    // workspace carve (256B aligned)
    char* ws = (char*)d_ws;
    size_t off = 0;
    auto carve = [&](size_t bytes) -> char* {
        char* p = ws + off;
        off = (off + bytes + 255) & ~(size_t)255;
        return p;
    };
    float* bufA = (float*)carve((size_t)N * 256 * 4);   // xl  (and xl3)
    float* bufB = (float*)carve((size_t)N * 256 * 4);   // xr  (and xr3)
    float* bufC = (float*)carve((size_t)N * 256 * 4);   // h
    int* cnt        = (int*)carve((size_t)N * 4);
    int* row_ptr    = (int*)carve((size_t)(N + 1) * 4);
    int* cursor     = (int*)carve((size_t)N * 4);
    int* src_sorted = (int*)carve((size_t)Et * 4);
    int* bsums      = (int*)carve(1024 * 4);

    const int gN  = (N + 255) / 256;
    const int gEt = (Et + 255) / 256;

    // --- CSR build ---
    hipMemsetAsync(cnt, 0, (size_t)N * 4, stream);
    k_count<<<gEt, 256, 0, stream>>>(ei, E, Et, cnt);
    k_scan_block<<<gN, 256, 0, stream>>>(cnt, row_ptr, bsums, N);
    k_scan_bsums<<<1, 256, 0, stream>>>(bsums, gN);
    k_scan_add<<<gN, 256, 0, stream>>>(row_ptr, bsums, N, Et);
    k_cursor_init<<<gN, 256, 0, stream>>>(row_ptr, cursor, N);
    k_scatter<<<gEt, 256, 0, stream>>>(ei, E, Et, cursor, src_sorted);

    dim3 gemm_grid((N + 63) / 64, 4);

    // --- Layer 1 ---
    k_gemm_pair<<<gemm_grid, 256, 0, stream>>>(x, N, F, Wl1, Wr1, bl1, br1, bufA, bufB);
    k_agg256<<<N, 256, 0, stream>>>(bufA, bufB, row_ptr, src_sorted, att1, bias1, bufC);

    // --- Layer 2 ---
    k_gemm_pair<<<gemm_grid, 256, 0, stream>>>(bufC, N, 256, Wl2, Wr2, bl2, br2, bufA, bufB);
    k_agg256<<<N, 256, 0, stream>>>(bufA, bufB, row_ptr, src_sorted, att2, bias2, bufC);

    // --- Layer 3 ---
    float* xl3 = bufA;
    float* xr3 = bufB;
    k_gemm3<<<N, 64, 0, stream>>>(bufC, Wl3, Wr3, bl3, br3, xl3, xr3);
    k_agg3<<<gN, 256, 0, stream>>>(xl3, xr3, row_ptr, src_sorted, att3, bias3,
                                   (float*)d_out, N);
}

// Round 2
// 689.346 us; speedup vs baseline: 1.3092x; 1.3092x over previous
//
#include <hip/hip_runtime.h>
#include <math.h>

#define NEG_SLOPE 0.2f

// ---------------- CSR build ----------------

__global__ __launch_bounds__(256) void k_count(const int* __restrict__ ei, int E, int Et,
                                               int* __restrict__ cnt) {
    int e = blockIdx.x * 256 + threadIdx.x;
    if (e < Et) {
        int d = (e < E) ? ei[E + e] : (e - E);   // self-loop edges at the tail
        atomicAdd(&cnt[d], 1);
    }
}

__global__ __launch_bounds__(256) void k_scan_block(const int* __restrict__ cnt,
                                                    int* __restrict__ out,
                                                    int* __restrict__ bsums, int n) {
    __shared__ int tmp[256];
    int t = threadIdx.x;
    int i = blockIdx.x * 256 + t;
    int v = (i < n) ? cnt[i] : 0;
    tmp[t] = v;
    __syncthreads();
    for (int d = 1; d < 256; d <<= 1) {
        int add = (t >= d) ? tmp[t - d] : 0;
        __syncthreads();
        tmp[t] += add;
        __syncthreads();
    }
    if (i < n) out[i] = tmp[t] - v;              // exclusive scan within block
    if (t == 255) bsums[blockIdx.x] = tmp[t];    // block total
}

__global__ __launch_bounds__(256) void k_scan_bsums(int* bsums, int nb) {
    __shared__ int tmp[256];
    int t = threadIdx.x;
    int v = (t < nb) ? bsums[t] : 0;
    tmp[t] = v;
    __syncthreads();
    for (int d = 1; d < 256; d <<= 1) {
        int add = (t >= d) ? tmp[t - d] : 0;
        __syncthreads();
        tmp[t] += add;
        __syncthreads();
    }
    if (t < nb) bsums[t] = tmp[t] - v;           // exclusive block offsets
}

__global__ __launch_bounds__(256) void k_scan_add(int* __restrict__ out,
                                                  const int* __restrict__ bsums,
                                                  int n, int total) {
    int i = blockIdx.x * 256 + threadIdx.x;
    if (i < n) out[i] += bsums[blockIdx.x];
    if (i == 0) out[n] = total;                  // row_ptr[N] = Et
}

__global__ __launch_bounds__(256) void k_cursor_init(const int* __restrict__ row_ptr,
                                                     int* __restrict__ cursor, int n) {
    int i = blockIdx.x * 256 + threadIdx.x;
    if (i < n) cursor[i] = row_ptr[i];
}

__global__ __launch_bounds__(256) void k_scatter(const int* __restrict__ ei, int E, int Et,
                                                 int* __restrict__ cursor,
                                                 int* __restrict__ src_sorted) {
    int e = blockIdx.x * 256 + threadIdx.x;
    if (e < Et) {
        int s, d;
        if (e < E) { s = ei[e]; d = ei[E + e]; } else { s = d = e - E; }
        int pos = atomicAdd(&cursor[d], 1);
        src_sorted[pos] = s;
    }
}

// ---------------- Tiled fp32 GEMM: [M,K] @ {Wl,Wr}[K,256] + bias ----------------
// 128x64 tile per block; both weight matrices share the A tile.
// Per thread: 8 rows x 4 cols x 2 matrices = 64 FMA per kk vs 4 LDS b128 reads.

__global__ __launch_bounds__(256) void k_gemm_pair(const float* __restrict__ A, int M, int K,
                                                   const float* __restrict__ Wl,
                                                   const float* __restrict__ Wr,
                                                   const float* __restrict__ bl,
                                                   const float* __restrict__ br,
                                                   float* __restrict__ Cl,
                                                   float* __restrict__ Cr) {
    __shared__ float Ast[16][132];   // transposed A tile: Ast[k][m], 128 rows
    __shared__ float Bls[16][68];
    __shared__ float Brs[16][68];
    const int row0 = blockIdx.x * 128;
    const int col0 = blockIdx.y * 64;
    const int t  = threadIdx.x;
    const int tx = t & 15;           // col group: cols tx*4 .. tx*4+3
    const int ty = t >> 4;           // row group: rows ty*8 .. ty*8+7
    float accl[8][4] = {{0.f}}, accr[8][4] = {{0.f}};

    for (int k0 = 0; k0 < K; k0 += 16) {
        // A tile 128x16 (transposed into LDS), 8 scalars/thread
        #pragma unroll
        for (int i = 0; i < 8; i++) {
            int idx = t + i * 256;           // 0..2047
            int r = idx >> 4, c = idx & 15;
            int gr = row0 + r, gk = k0 + c;
            Ast[c][r] = (gr < M && gk < K) ? A[(size_t)gr * K + gk] : 0.0f;
        }
        // B tiles 16x64, one float4 per thread per matrix
        {
            int r = t >> 4, c4 = t & 15;
            int gk = k0 + r;
            float4 vl = make_float4(0.f, 0.f, 0.f, 0.f);
            float4 vr = vl;
            if (gk < K) {
                vl = *(const float4*)&Wl[gk * 256 + col0 + c4 * 4];
                vr = *(const float4*)&Wr[gk * 256 + col0 + c4 * 4];
            }
            *(float4*)&Bls[r][c4 * 4] = vl;
            *(float4*)&Brs[r][c4 * 4] = vr;
        }
        __syncthreads();
        #pragma unroll
        for (int kk = 0; kk < 16; kk++) {
            float a[8], b[4], c2[4];
            #pragma unroll
            for (int i = 0; i < 8; i++) a[i]  = Ast[kk][ty * 8 + i];
            #pragma unroll
            for (int j = 0; j < 4; j++) b[j]  = Bls[kk][tx * 4 + j];
            #pragma unroll
            for (int j = 0; j < 4; j++) c2[j] = Brs[kk][tx * 4 + j];
            #pragma unroll
            for (int i = 0; i < 8; i++)
                #pragma unroll
                for (int j = 0; j < 4; j++) {
                    accl[i][j] = fmaf(a[i], b[j],  accl[i][j]);
                    accr[i][j] = fmaf(a[i], c2[j], accr[i][j]);
                }
        }
        __syncthreads();
    }
    const float4 blv = *(const float4*)&bl[col0 + tx * 4];
    const float4 brv = *(const float4*)&br[col0 + tx * 4];
    #pragma unroll
    for (int i = 0; i < 8; i++) {
        int gr = row0 + ty * 8 + i;
        if (gr < M) {
            float4 ol, orr;
            ol.x  = accl[i][0] + blv.x; ol.y  = accl[i][1] + blv.y;
            ol.z  = accl[i][2] + blv.z; ol.w  = accl[i][3] + blv.w;
            orr.x = accr[i][0] + brv.x; orr.y = accr[i][1] + brv.y;
            orr.z = accr[i][2] + brv.z; orr.w = accr[i][3] + brv.w;
            *(float4*)&Cl[(size_t)gr * 256 + col0 + tx * 4] = ol;
            *(float4*)&Cr[(size_t)gr * 256 + col0 + tx * 4] = orr;
        }
    }
}

// ---------------- Aggregation for layers 1&2 (H=4, C=64), online softmax ----------------
// Wave-per-node. Lane l owns channels 4l..4l+3 (all in head l>>4), so:
//  - one float4 load fetches this wave's slice of an entire xl row (1 KB / instr)
//  - the per-head logit reduction is 4 shfl_xor steps within a 16-lane group
// Edges processed in batches of 4 for load/shfl ILP; one exp-rescale per batch.

__global__ __launch_bounds__(256) void k_agg256(const float* __restrict__ xl,
                                                const float* __restrict__ xr,
                                                const int* __restrict__ row_ptr,
                                                const int* __restrict__ src_sorted,
                                                const float* __restrict__ att,
                                                const float* __restrict__ bias,
                                                float* __restrict__ h_out, int N) {
    const int wave = threadIdx.x >> 6;
    const int lane = threadIdx.x & 63;
    const int n = blockIdx.x * 4 + wave;
    if (n >= N) return;
    const int ci = lane * 4;
    const float4 xr4 = *(const float4*)&xr[(size_t)n * 256 + ci];
    const float4 at4 = *(const float4*)&att[ci];
    float4 acc = make_float4(0.f, 0.f, 0.f, 0.f);
    float m = -INFINITY, s = 0.0f;
    const int beg = row_ptr[n], end = row_ptr[n + 1];

    for (int base = beg; base < end; base += 64) {
        const int cnt = min(64, end - base);
        const int sv_r = src_sorted[base + min(lane, cnt - 1)];
        for (int j0 = 0; j0 < cnt; j0 += 4) {
            float4 xv[4];
            float lg[4];
            #pragma unroll
            for (int e = 0; e < 4; e++) {
                int sv = __shfl(sv_r, j0 + e, 64);
                xv[e] = *(const float4*)&xl[(size_t)sv * 256 + ci];
            }
            #pragma unroll
            for (int e = 0; e < 4; e++) {
                float tx0 = xv[e].x + xr4.x, tx1 = xv[e].y + xr4.y;
                float tx2 = xv[e].z + xr4.z, tx3 = xv[e].w + xr4.w;
                tx0 = tx0 > 0.f ? tx0 : NEG_SLOPE * tx0;
                tx1 = tx1 > 0.f ? tx1 : NEG_SLOPE * tx1;
                tx2 = tx2 > 0.f ? tx2 : NEG_SLOPE * tx2;
                tx3 = tx3 > 0.f ? tx3 : NEG_SLOPE * tx3;
                lg[e] = at4.x * tx0 + at4.y * tx1 + at4.z * tx2 + at4.w * tx3;
            }
            #pragma unroll
            for (int d = 1; d < 16; d <<= 1)
                #pragma unroll
                for (int e = 0; e < 4; e++)
                    lg[e] += __shfl_xor(lg[e], d, 64);
            #pragma unroll
            for (int e = 0; e < 4; e++)
                if (j0 + e >= cnt) lg[e] = -INFINITY;
            float bm = fmaxf(fmaxf(lg[0], lg[1]), fmaxf(lg[2], lg[3]));
            float nm = fmaxf(m, bm);
            float sc = __expf(m - nm);
            acc.x *= sc; acc.y *= sc; acc.z *= sc; acc.w *= sc;
            s *= sc;
            #pragma unroll
            for (int e = 0; e < 4; e++) {
                float p = __expf(lg[e] - nm);
                s += p;
                acc.x += p * xv[e].x;
                acc.y += p * xv[e].y;
                acc.z += p * xv[e].z;
                acc.w += p * xv[e].w;
            }
            m = nm;
        }
    }
    const float inv = 1.0f / s;
    const float4 bv = *(const float4*)&bias[ci];
    float4 o;
    o.x = acc.x * inv + bv.x;
    o.y = acc.y * inv + bv.y;
    o.z = acc.z * inv + bv.z;
    o.w = acc.w * inv + bv.w;
    o.x = o.x > 0.f ? o.x : (__expf(o.x) - 1.f);
    o.y = o.y > 0.f ? o.y : (__expf(o.y) - 1.f);
    o.z = o.z > 0.f ? o.z : (__expf(o.z) - 1.f);
    o.w = o.w > 0.f ? o.w : (__expf(o.w) - 1.f);
    *(float4*)&h_out[(size_t)n * 256 + ci] = o;
}

// ---------------- Layer 3: 256 -> 6 transform (wave-per-node) ----------------

__global__ __launch_bounds__(256) void k_gemm3(const float* __restrict__ h,
                                               const float* __restrict__ Wl,
                                               const float* __restrict__ Wr,
                                               const float* __restrict__ bl,
                                               const float* __restrict__ br,
                                               float* __restrict__ xl3,
                                               float* __restrict__ xr3, int N) {
    const int wave = threadIdx.x >> 6;
    const int lane = threadIdx.x & 63;
    const int n = blockIdx.x * 4 + wave;
    if (n >= N) return;
    float hv[4];
    #pragma unroll
    for (int i = 0; i < 4; i++) hv[i] = h[(size_t)n * 256 + lane + i * 64];
    #pragma unroll
    for (int j = 0; j < 6; j++) {
        float pl = 0.0f, pr = 0.0f;
        #pragma unroll
        for (int i = 0; i < 4; i++) {
            int k = lane + i * 64;
            pl = fmaf(hv[i], Wl[k * 6 + j], pl);
            pr = fmaf(hv[i], Wr[k * 6 + j], pr);
        }
        #pragma unroll
        for (int d = 1; d < 64; d <<= 1) {
            pl += __shfl_xor(pl, d, 64);
            pr += __shfl_xor(pr, d, 64);
        }
        if (lane == 0) {
            xl3[n * 6 + j] = pl + bl[j];
            xr3[n * 6 + j] = pr + br[j];
        }
    }
}

// ---------------- Layer 3 aggregation (H=6, C=1, mean over heads) ----------------

__global__ __launch_bounds__(256) void k_agg3(const float* __restrict__ xl3,
                                              const float* __restrict__ xr3,
                                              const int* __restrict__ row_ptr,
                                              const int* __restrict__ src_sorted,
                                              const float* __restrict__ att3,
                                              const float* __restrict__ bias3,
                                              float* __restrict__ out, int N) {
    int n = blockIdx.x * 256 + threadIdx.x;
    if (n >= N) return;
    float xrv[6], attv[6], m[6], s[6], acc[6];
    #pragma unroll
    for (int j = 0; j < 6; j++) {
        xrv[j] = xr3[n * 6 + j];
        attv[j] = att3[j];
        m[j] = -INFINITY; s[j] = 0.0f; acc[j] = 0.0f;
    }
    int beg = row_ptr[n], end = row_ptr[n + 1];
    for (int idx = beg; idx < end; idx++) {
        int sv = src_sorted[idx];
        #pragma unroll
        for (int j = 0; j < 6; j++) {
            float xlv = xl3[sv * 6 + j];
            float tt = xlv + xrv[j];
            float lr = tt > 0.0f ? tt : NEG_SLOPE * tt;
            float logit = attv[j] * lr;
            float nm = fmaxf(m[j], logit);
            float sc = __expf(m[j] - nm);
            float p  = __expf(logit - nm);
            acc[j] = acc[j] * sc + p * xlv;
            s[j]   = s[j] * sc + p;
            m[j]   = nm;
        }
    }
    float o = 0.0f;
    #pragma unroll
    for (int j = 0; j < 6; j++) o += acc[j] / s[j];
    out[n] = o * (1.0f / 6.0f) + bias3[0];
}

// ---------------- launch ----------------

extern "C" void kernel_launch(void* const* d_in, const int* in_sizes, int n_in,
                              void* d_out, int out_size, void* d_ws, size_t ws_size,
                              hipStream_t stream) {
    const float* x    = (const float*)d_in[0];
    const int*   ei   = (const int*)  d_in[1];
    const float* Wl1  = (const float*)d_in[2];
    const float* bl1  = (const float*)d_in[3];
    const float* Wr1  = (const float*)d_in[4];
    const float* br1  = (const float*)d_in[5];
    const float* att1 = (const float*)d_in[6];
    const float* bias1= (const float*)d_in[7];
    const float* Wl2  = (const float*)d_in[8];
    const float* bl2  = (const float*)d_in[9];
    const float* Wr2  = (const float*)d_in[10];
    const float* br2  = (const float*)d_in[11];
    const float* att2 = (const float*)d_in[12];
    const float* bias2= (const float*)d_in[13];
    const float* Wl3  = (const float*)d_in[14];
    const float* bl3  = (const float*)d_in[15];
    const float* Wr3  = (const float*)d_in[16];
    const float* br3  = (const float*)d_in[17];
    const float* att3 = (const float*)d_in[18];
    const float* bias3= (const float*)d_in[19];

    const int F  = in_sizes[2] / 256;   // 58
    const int N  = in_sizes[0] / F;     // 50000
    const int E  = in_sizes[1] / 2;     // 500000
    const int Et = E + N;

    // workspace carve (256B aligned)
    char* ws = (char*)d_ws;
    size_t off = 0;
    auto carve = [&](size_t bytes) -> char* {
        char* p = ws + off;
        off = (off + bytes + 255) & ~(size_t)255;
        return p;
    };
    float* bufA = (float*)carve((size_t)N * 256 * 4);   // xl  (and xl3)
    float* bufB = (float*)carve((size_t)N * 256 * 4);   // xr  (and xr3)
    float* bufC = (float*)carve((size_t)N * 256 * 4);   // h
    int* cnt        = (int*)carve((size_t)N * 4);
    int* row_ptr    = (int*)carve((size_t)(N + 1) * 4);
    int* cursor     = (int*)carve((size_t)N * 4);
    int* src_sorted = (int*)carve((size_t)Et * 4);
    int* bsums      = (int*)carve(1024 * 4);

    const int gN  = (N + 255) / 256;
    const int gEt = (Et + 255) / 256;
    const int gW  = (N + 3) / 4;        // wave-per-node kernels

    // --- CSR build ---
    hipMemsetAsync(cnt, 0, (size_t)N * 4, stream);
    k_count<<<gEt, 256, 0, stream>>>(ei, E, Et, cnt);
    k_scan_block<<<gN, 256, 0, stream>>>(cnt, row_ptr, bsums, N);
    k_scan_bsums<<<1, 256, 0, stream>>>(bsums, gN);
    k_scan_add<<<gN, 256, 0, stream>>>(row_ptr, bsums, N, Et);
    k_cursor_init<<<gN, 256, 0, stream>>>(row_ptr, cursor, N);
    k_scatter<<<gEt, 256, 0, stream>>>(ei, E, Et, cursor, src_sorted);

    dim3 gemm_grid((N + 127) / 128, 4);

    // --- Layer 1 ---
    k_gemm_pair<<<gemm_grid, 256, 0, stream>>>(x, N, F, Wl1, Wr1, bl1, br1, bufA, bufB);
    k_agg256<<<gW, 256, 0, stream>>>(bufA, bufB, row_ptr, src_sorted, att1, bias1, bufC, N);

    // --- Layer 2 ---
    k_gemm_pair<<<gemm_grid, 256, 0, stream>>>(bufC, N, 256, Wl2, Wr2, bl2, br2, bufA, bufB);
    k_agg256<<<gW, 256, 0, stream>>>(bufA, bufB, row_ptr, src_sorted, att2, bias2, bufC, N);

    // --- Layer 3 ---
    float* xl3 = bufA;
    float* xr3 = bufB;
    k_gemm3<<<gW, 256, 0, stream>>>(bufC, Wl3, Wr3, bl3, br3, xl3, xr3, N);
    k_agg3<<<gN, 256, 0, stream>>>(xl3, xr3, row_ptr, src_sorted, att3, bias3,
                                   (float*)d_out, N);
}

// Round 3
// 475.329 us; speedup vs baseline: 1.8986x; 1.4502x over previous
//
#include <hip/hip_runtime.h>
#include <math.h>

#define NEG_SLOPE 0.2f

typedef __attribute__((ext_vector_type(8))) short bf16x8;
typedef __attribute__((ext_vector_type(4))) float f32x4;

__device__ inline unsigned short f2bf(float f) {
    unsigned u = __float_as_uint(f);
    u += 0x7fffu + ((u >> 16) & 1u);          // round-to-nearest-even
    return (unsigned short)(u >> 16);
}
__device__ inline float bf_lo(unsigned u) { return __uint_as_float(u << 16); }
__device__ inline float bf_hi(unsigned u) { return __uint_as_float(u & 0xffff0000u); }

// ---------------- CSR build ----------------

__global__ __launch_bounds__(256) void k_count(const int* __restrict__ ei, int E, int Et,
                                               int* __restrict__ cnt) {
    int e = blockIdx.x * 256 + threadIdx.x;
    if (e < Et) {
        int d = (e < E) ? ei[E + e] : (e - E);
        atomicAdd(&cnt[d], 1);
    }
}

__global__ __launch_bounds__(256) void k_scan_block(const int* __restrict__ cnt,
                                                    int* __restrict__ out,
                                                    int* __restrict__ bsums, int n) {
    __shared__ int tmp[256];
    int t = threadIdx.x;
    int i = blockIdx.x * 256 + t;
    int v = (i < n) ? cnt[i] : 0;
    tmp[t] = v;
    __syncthreads();
    for (int d = 1; d < 256; d <<= 1) {
        int add = (t >= d) ? tmp[t - d] : 0;
        __syncthreads();
        tmp[t] += add;
        __syncthreads();
    }
    if (i < n) out[i] = tmp[t] - v;
    if (t == 255) bsums[blockIdx.x] = tmp[t];
}

__global__ __launch_bounds__(256) void k_scan_bsums(int* bsums, int nb) {
    __shared__ int tmp[256];
    int t = threadIdx.x;
    int v = (t < nb) ? bsums[t] : 0;
    tmp[t] = v;
    __syncthreads();
    for (int d = 1; d < 256; d <<= 1) {
        int add = (t >= d) ? tmp[t - d] : 0;
        __syncthreads();
        tmp[t] += add;
        __syncthreads();
    }
    if (t < nb) bsums[t] = tmp[t] - v;
}

__global__ __launch_bounds__(256) void k_scan_add(int* __restrict__ out,
                                                  const int* __restrict__ bsums,
                                                  int n, int total) {
    int i = blockIdx.x * 256 + threadIdx.x;
    if (i < n) out[i] += bsums[blockIdx.x];
    if (i == 0) out[n] = total;
}

__global__ __launch_bounds__(256) void k_cursor_init(const int* __restrict__ row_ptr,
                                                     int* __restrict__ cursor, int n) {
    int i = blockIdx.x * 256 + threadIdx.x;
    if (i < n) cursor[i] = row_ptr[i];
}

__global__ __launch_bounds__(256) void k_scatter(const int* __restrict__ ei, int E, int Et,
                                                 int* __restrict__ cursor,
                                                 int* __restrict__ src_sorted) {
    int e = blockIdx.x * 256 + threadIdx.x;
    if (e < Et) {
        int s, d;
        if (e < E) { s = ei[e]; d = ei[E + e]; } else { s = d = e - E; }
        int pos = atomicAdd(&cursor[d], 1);
        src_sorted[pos] = s;
    }
}

// ---------------- casts ----------------

// x [N x F] fp32 -> xb [N x (1<<kshift)] bf16, zero-padded in k
__global__ __launch_bounds__(256) void k_cast_x(const float* __restrict__ x,
                                                unsigned short* __restrict__ xb,
                                                int N, int F, int kshift) {
    int i = blockIdx.x * 256 + threadIdx.x;
    if (i < (N << kshift)) {
        int n = i >> kshift, k = i & ((1 << kshift) - 1);
        float v = (k < F) ? x[n * F + k] : 0.0f;
        xb[i] = f2bf(v);
    }
}

// W [K x 256] fp32 -> Wt [256 x (1<<kshift)] bf16 TRANSPOSED, zero-padded in k
__global__ __launch_bounds__(256) void k_cast_wt(const float* __restrict__ W,
                                                 unsigned short* __restrict__ Wt,
                                                 int K, int kshift) {
    int i = blockIdx.x * 256 + threadIdx.x;
    if (i < (256 << kshift)) {
        int n = i >> kshift, k = i & ((1 << kshift) - 1);
        Wt[i] = f2bf(k < K ? W[k * 256 + n] : 0.0f);
    }
}

// ---------------- MFMA bf16 GEMM pair: A[M x Kp] @ {Wl,Wr}^T + bias -> bf16 ----------------
// 128x128 tile per block, 2x2 wave grid, 4x4 16x16x32 mfma tiles per wave.
// Both A and Wt stored k-contiguous -> all fragment loads are ds_read_b128.
// LDS rows padded to 40 bf16 (80 B = 20 banks) -> 2-way max (free).

#define LDST 40

__global__ __launch_bounds__(256) void k_gemm_pair_mfma(
        const unsigned short* __restrict__ A, int M, int Kp,
        const unsigned short* __restrict__ Btl, const unsigned short* __restrict__ Btr,
        const float* __restrict__ bl, const float* __restrict__ br,
        unsigned short* __restrict__ Cl, unsigned short* __restrict__ Cr) {
    __shared__ unsigned short As[128 * LDST];
    __shared__ unsigned short Bs[128 * LDST];
    const int t = threadIdx.x;
    const int wave = t >> 6, lane = t & 63;
    const int wr = wave >> 1, wc = wave & 1;
    const int l15 = lane & 15, l4 = lane >> 4;
    const int row0 = blockIdx.x * 128;
    const int mat  = blockIdx.y >> 1;
    const int col0 = (blockIdx.y & 1) * 128;
    const unsigned short* Bt = mat ? Btr : Btl;
    const float* bias        = mat ? br  : bl;
    unsigned short* C        = mat ? Cr  : Cl;

    f32x4 acc[4][4];
    #pragma unroll
    for (int a = 0; a < 4; a++)
        #pragma unroll
        for (int b = 0; b < 4; b++)
            acc[a][b] = (f32x4){0.f, 0.f, 0.f, 0.f};

    for (int k0 = 0; k0 < Kp; k0 += 32) {
        #pragma unroll
        for (int i = 0; i < 2; i++) {
            int s = t + i * 256;          // 0..511
            int r = s >> 2, ks = (s & 3) * 8;
            int gr = row0 + r;
            uint4 va = make_uint4(0u, 0u, 0u, 0u);
            if (gr < M) va = *(const uint4*)&A[(size_t)gr * Kp + k0 + ks];
            *(uint4*)&As[r * LDST + ks] = va;
            uint4 vb = *(const uint4*)&Bt[(size_t)(col0 + r) * Kp + k0 + ks];
            *(uint4*)&Bs[r * LDST + ks] = vb;
        }
        __syncthreads();
        bf16x8 af[4], bfr[4];
        #pragma unroll
        for (int mt = 0; mt < 4; mt++)
            af[mt] = *(const bf16x8*)&As[(wr * 64 + mt * 16 + l15) * LDST + l4 * 8];
        #pragma unroll
        for (int nt = 0; nt < 4; nt++)
            bfr[nt] = *(const bf16x8*)&Bs[(wc * 64 + nt * 16 + l15) * LDST + l4 * 8];
        #pragma unroll
        for (int mt = 0; mt < 4; mt++)
            #pragma unroll
            for (int nt = 0; nt < 4; nt++)
                acc[mt][nt] = __builtin_amdgcn_mfma_f32_16x16x32_bf16(
                    af[mt], bfr[nt], acc[mt][nt], 0, 0, 0);
        __syncthreads();
    }
    #pragma unroll
    for (int nt = 0; nt < 4; nt++) {
        int gc = col0 + wc * 64 + nt * 16 + l15;
        float bv = bias[gc];
        #pragma unroll
        for (int mt = 0; mt < 4; mt++) {
            #pragma unroll
            for (int r = 0; r < 4; r++) {
                int gr = row0 + wr * 64 + mt * 16 + l4 * 4 + r;
                if (gr < M)
                    C[(size_t)gr * 256 + gc] = f2bf(acc[mt][nt][r] + bv);
            }
        }
    }
}

// ---------------- Aggregation layers 1&2 (H=4, C=64), bf16 tables, online softmax ----------------

__global__ __launch_bounds__(256) void k_agg256(const unsigned short* __restrict__ xl,
                                                const unsigned short* __restrict__ xr,
                                                const int* __restrict__ row_ptr,
                                                const int* __restrict__ src_sorted,
                                                const float* __restrict__ att,
                                                const float* __restrict__ bias,
                                                unsigned short* __restrict__ h_out, int N) {
    const int wave = threadIdx.x >> 6;
    const int lane = threadIdx.x & 63;
    const int n = blockIdx.x * 4 + wave;
    if (n >= N) return;
    const int ci = lane * 4;
    uint2 xru = *(const uint2*)&xr[(size_t)n * 256 + ci];
    const float xr0 = bf_lo(xru.x), xr1 = bf_hi(xru.x);
    const float xr2 = bf_lo(xru.y), xr3 = bf_hi(xru.y);
    const float4 at4 = *(const float4*)&att[ci];
    float4 acc = make_float4(0.f, 0.f, 0.f, 0.f);
    float m = -INFINITY, s = 0.0f;
    const int beg = row_ptr[n], end = row_ptr[n + 1];

    for (int base = beg; base < end; base += 64) {
        const int cnt = min(64, end - base);
        const int sv_r = src_sorted[base + min(lane, cnt - 1)];
        for (int j0 = 0; j0 < cnt; j0 += 4) {
            float xv[4][4];
            float lg[4];
            #pragma unroll
            for (int e = 0; e < 4; e++) {
                int sv = __shfl(sv_r, j0 + e, 64);
                uint2 u = *(const uint2*)&xl[(size_t)sv * 256 + ci];
                xv[e][0] = bf_lo(u.x); xv[e][1] = bf_hi(u.x);
                xv[e][2] = bf_lo(u.y); xv[e][3] = bf_hi(u.y);
            }
            #pragma unroll
            for (int e = 0; e < 4; e++) {
                float t0 = xv[e][0] + xr0, t1 = xv[e][1] + xr1;
                float t2 = xv[e][2] + xr2, t3 = xv[e][3] + xr3;
                t0 = t0 > 0.f ? t0 : NEG_SLOPE * t0;
                t1 = t1 > 0.f ? t1 : NEG_SLOPE * t1;
                t2 = t2 > 0.f ? t2 : NEG_SLOPE * t2;
                t3 = t3 > 0.f ? t3 : NEG_SLOPE * t3;
                lg[e] = at4.x * t0 + at4.y * t1 + at4.z * t2 + at4.w * t3;
            }
            #pragma unroll
            for (int d = 1; d < 16; d <<= 1)
                #pragma unroll
                for (int e = 0; e < 4; e++)
                    lg[e] += __shfl_xor(lg[e], d, 64);
            #pragma unroll
            for (int e = 0; e < 4; e++)
                if (j0 + e >= cnt) lg[e] = -INFINITY;
            float bm = fmaxf(fmaxf(lg[0], lg[1]), fmaxf(lg[2], lg[3]));
            float nm = fmaxf(m, bm);
            float sc = __expf(m - nm);
            acc.x *= sc; acc.y *= sc; acc.z *= sc; acc.w *= sc;
            s *= sc;
            #pragma unroll
            for (int e = 0; e < 4; e++) {
                float p = __expf(lg[e] - nm);
                s += p;
                acc.x += p * xv[e][0];
                acc.y += p * xv[e][1];
                acc.z += p * xv[e][2];
                acc.w += p * xv[e][3];
            }
            m = nm;
        }
    }
    const float inv = 1.0f / s;
    const float4 bv = *(const float4*)&bias[ci];
    float o0 = acc.x * inv + bv.x;
    float o1 = acc.y * inv + bv.y;
    float o2 = acc.z * inv + bv.z;
    float o3 = acc.w * inv + bv.w;
    o0 = o0 > 0.f ? o0 : (__expf(o0) - 1.f);
    o1 = o1 > 0.f ? o1 : (__expf(o1) - 1.f);
    o2 = o2 > 0.f ? o2 : (__expf(o2) - 1.f);
    o3 = o3 > 0.f ? o3 : (__expf(o3) - 1.f);
    ushort4 hv;
    hv.x = f2bf(o0); hv.y = f2bf(o1); hv.z = f2bf(o2); hv.w = f2bf(o3);
    *(ushort4*)&h_out[(size_t)n * 256 + ci] = hv;
}

// ---------------- Layer 3: 256 -> 6 transform (wave-per-node, bf16 input) ----------------

__global__ __launch_bounds__(256) void k_gemm3(const unsigned short* __restrict__ h,
                                               const float* __restrict__ Wl,
                                               const float* __restrict__ Wr,
                                               const float* __restrict__ bl,
                                               const float* __restrict__ br,
                                               float* __restrict__ xl3,
                                               float* __restrict__ xr3, int N) {
    const int wave = threadIdx.x >> 6;
    const int lane = threadIdx.x & 63;
    const int n = blockIdx.x * 4 + wave;
    if (n >= N) return;
    float hv[4];
    #pragma unroll
    for (int i = 0; i < 4; i++)
        hv[i] = bf_lo((unsigned)h[(size_t)n * 256 + lane + i * 64]);
    #pragma unroll
    for (int j = 0; j < 6; j++) {
        float pl = 0.0f, pr = 0.0f;
        #pragma unroll
        for (int i = 0; i < 4; i++) {
            int k = lane + i * 64;
            pl = fmaf(hv[i], Wl[k * 6 + j], pl);
            pr = fmaf(hv[i], Wr[k * 6 + j], pr);
        }
        #pragma unroll
        for (int d = 1; d < 64; d <<= 1) {
            pl += __shfl_xor(pl, d, 64);
            pr += __shfl_xor(pr, d, 64);
        }
        if (lane == 0) {
            xl3[n * 6 + j] = pl + bl[j];
            xr3[n * 6 + j] = pr + br[j];
        }
    }
}

// ---------------- Layer 3 aggregation (H=6, C=1, mean over heads) ----------------

__global__ __launch_bounds__(256) void k_agg3(const float* __restrict__ xl3,
                                              const float* __restrict__ xr3,
                                              const int* __restrict__ row_ptr,
                                              const int* __restrict__ src_sorted,
                                              const float* __restrict__ att3,
                                              const float* __restrict__ bias3,
                                              float* __restrict__ out, int N) {
    int n = blockIdx.x * 256 + threadIdx.x;
    if (n >= N) return;
    float xrv[6], attv[6], m[6], s[6], acc[6];
    #pragma unroll
    for (int j = 0; j < 6; j++) {
        xrv[j] = xr3[n * 6 + j];
        attv[j] = att3[j];
        m[j] = -INFINITY; s[j] = 0.0f; acc[j] = 0.0f;
    }
    int beg = row_ptr[n], end = row_ptr[n + 1];
    for (int idx = beg; idx < end; idx++) {
        int sv = src_sorted[idx];
        #pragma unroll
        for (int j = 0; j < 6; j++) {
            float xlv = xl3[sv * 6 + j];
            float tt = xlv + xrv[j];
            float lr = tt > 0.0f ? tt : NEG_SLOPE * tt;
            float logit = attv[j] * lr;
            float nm = fmaxf(m[j], logit);
            float sc = __expf(m[j] - nm);
            float p  = __expf(logit - nm);
            acc[j] = acc[j] * sc + p * xlv;
            s[j]   = s[j] * sc + p;
            m[j]   = nm;
        }
    }
    float o = 0.0f;
    #pragma unroll
    for (int j = 0; j < 6; j++) o += acc[j] / s[j];
    out[n] = o * (1.0f / 6.0f) + bias3[0];
}

// ---------------- launch ----------------

extern "C" void kernel_launch(void* const* d_in, const int* in_sizes, int n_in,
                              void* d_out, int out_size, void* d_ws, size_t ws_size,
                              hipStream_t stream) {
    const float* x    = (const float*)d_in[0];
    const int*   ei   = (const int*)  d_in[1];
    const float* Wl1  = (const float*)d_in[2];
    const float* bl1  = (const float*)d_in[3];
    const float* Wr1  = (const float*)d_in[4];
    const float* br1  = (const float*)d_in[5];
    const float* att1 = (const float*)d_in[6];
    const float* bias1= (const float*)d_in[7];
    const float* Wl2  = (const float*)d_in[8];
    const float* bl2  = (const float*)d_in[9];
    const float* Wr2  = (const float*)d_in[10];
    const float* br2  = (const float*)d_in[11];
    const float* att2 = (const float*)d_in[12];
    const float* bias2= (const float*)d_in[13];
    const float* Wl3  = (const float*)d_in[14];
    const float* bl3  = (const float*)d_in[15];
    const float* Wr3  = (const float*)d_in[16];
    const float* br3  = (const float*)d_in[17];
    const float* att3 = (const float*)d_in[18];
    const float* bias3= (const float*)d_in[19];

    const int F  = in_sizes[2] / 256;   // 58
    const int N  = in_sizes[0] / F;     // 50000
    const int E  = in_sizes[1] / 2;     // 500000
    const int Et = E + N;

    char* ws = (char*)d_ws;
    size_t off = 0;
    auto carve = [&](size_t bytes) -> char* {
        char* p = ws + off;
        off = (off + bytes + 255) & ~(size_t)255;
        return p;
    };
    unsigned short* xb   = (unsigned short*)carve((size_t)N * 64 * 2);
    unsigned short* xlb  = (unsigned short*)carve((size_t)N * 256 * 2);
    unsigned short* xrb  = (unsigned short*)carve((size_t)N * 256 * 2);
    unsigned short* hb   = (unsigned short*)carve((size_t)N * 256 * 2);
    unsigned short* wtl1 = (unsigned short*)carve(256 * 64 * 2);
    unsigned short* wtr1 = (unsigned short*)carve(256 * 64 * 2);
    unsigned short* wtl2 = (unsigned short*)carve(256 * 256 * 2);
    unsigned short* wtr2 = (unsigned short*)carve(256 * 256 * 2);
    float* xl3 = (float*)carve((size_t)N * 6 * 4);
    float* xr3 = (float*)carve((size_t)N * 6 * 4);
    int* cnt        = (int*)carve((size_t)N * 4);
    int* row_ptr    = (int*)carve((size_t)(N + 1) * 4);
    int* cursor     = (int*)carve((size_t)N * 4);
    int* src_sorted = (int*)carve((size_t)Et * 4);
    int* bsums      = (int*)carve(1024 * 4);

    const int gN  = (N + 255) / 256;
    const int gEt = (Et + 255) / 256;
    const int gW  = (N + 3) / 4;

    // --- CSR build ---
    hipMemsetAsync(cnt, 0, (size_t)N * 4, stream);
    k_count<<<gEt, 256, 0, stream>>>(ei, E, Et, cnt);
    k_scan_block<<<gN, 256, 0, stream>>>(cnt, row_ptr, bsums, N);
    k_scan_bsums<<<1, 256, 0, stream>>>(bsums, gN);
    k_scan_add<<<gN, 256, 0, stream>>>(row_ptr, bsums, N, Et);
    k_cursor_init<<<gN, 256, 0, stream>>>(row_ptr, cursor, N);
    k_scatter<<<gEt, 256, 0, stream>>>(ei, E, Et, cursor, src_sorted);

    // --- casts ---
    k_cast_x<<<((N << 6) + 255) / 256, 256, 0, stream>>>(x, xb, N, F, 6);
    k_cast_wt<<<(256 << 6) / 256, 256, 0, stream>>>(Wl1, wtl1, F, 6);
    k_cast_wt<<<(256 << 6) / 256, 256, 0, stream>>>(Wr1, wtr1, F, 6);
    k_cast_wt<<<(256 << 8) / 256, 256, 0, stream>>>(Wl2, wtl2, 256, 8);
    k_cast_wt<<<(256 << 8) / 256, 256, 0, stream>>>(Wr2, wtr2, 256, 8);

    dim3 gemm_grid((N + 127) / 128, 4);

    // --- Layer 1 ---
    k_gemm_pair_mfma<<<gemm_grid, 256, 0, stream>>>(xb, N, 64, wtl1, wtr1, bl1, br1, xlb, xrb);
    k_agg256<<<gW, 256, 0, stream>>>(xlb, xrb, row_ptr, src_sorted, att1, bias1, hb, N);

    // --- Layer 2 ---
    k_gemm_pair_mfma<<<gemm_grid, 256, 0, stream>>>(hb, N, 256, wtl2, wtr2, bl2, br2, xlb, xrb);
    k_agg256<<<gW, 256, 0, stream>>>(xlb, xrb, row_ptr, src_sorted, att2, bias2, hb, N);

    // --- Layer 3 ---
    k_gemm3<<<gW, 256, 0, stream>>>(hb, Wl3, Wr3, bl3, br3, xl3, xr3, N);
    k_agg3<<<gN, 256, 0, stream>>>(xl3, xr3, row_ptr, src_sorted, att3, bias3,
                                   (float*)d_out, N);
}

// Round 4
// 403.243 us; speedup vs baseline: 2.2381x; 1.1788x over previous
//
#include <hip/hip_runtime.h>
#include <math.h>

#define NEG_SLOPE 0.2f

typedef __attribute__((ext_vector_type(8))) short bf16x8;
typedef __attribute__((ext_vector_type(4))) float f32x4;

__device__ inline unsigned short f2bf(float f) {
    unsigned u = __float_as_uint(f);
    u += 0x7fffu + ((u >> 16) & 1u);          // round-to-nearest-even
    return (unsigned short)(u >> 16);
}
__device__ inline float bf_lo(unsigned u) { return __uint_as_float(u << 16); }
__device__ inline float bf_hi(unsigned u) { return __uint_as_float(u & 0xffff0000u); }

// ---------------- CSR build ----------------

__global__ __launch_bounds__(256) void k_count(const int* __restrict__ ei, int E, int Et,
                                               int* __restrict__ cnt) {
    int e = blockIdx.x * 256 + threadIdx.x;
    if (e < Et) {
        int d = (e < E) ? ei[E + e] : (e - E);
        atomicAdd(&cnt[d], 1);
    }
}

__global__ __launch_bounds__(256) void k_scan_block(const int* __restrict__ cnt,
                                                    int* __restrict__ out,
                                                    int* __restrict__ bsums, int n) {
    __shared__ int tmp[256];
    int t = threadIdx.x;
    int i = blockIdx.x * 256 + t;
    int v = (i < n) ? cnt[i] : 0;
    tmp[t] = v;
    __syncthreads();
    for (int d = 1; d < 256; d <<= 1) {
        int add = (t >= d) ? tmp[t - d] : 0;
        __syncthreads();
        tmp[t] += add;
        __syncthreads();
    }
    if (i < n) out[i] = tmp[t] - v;
    if (t == 255) bsums[blockIdx.x] = tmp[t];
}

__global__ __launch_bounds__(256) void k_scan_bsums(int* bsums, int nb) {
    __shared__ int tmp[256];
    int t = threadIdx.x;
    int v = (t < nb) ? bsums[t] : 0;
    tmp[t] = v;
    __syncthreads();
    for (int d = 1; d < 256; d <<= 1) {
        int add = (t >= d) ? tmp[t - d] : 0;
        __syncthreads();
        tmp[t] += add;
        __syncthreads();
    }
    if (t < nb) bsums[t] = tmp[t] - v;
}

__global__ __launch_bounds__(256) void k_scan_add(int* __restrict__ out,
                                                  const int* __restrict__ bsums,
                                                  int n, int total) {
    int i = blockIdx.x * 256 + threadIdx.x;
    if (i < n) out[i] += bsums[blockIdx.x];
    if (i == 0) out[n] = total;
}

__global__ __launch_bounds__(256) void k_cursor_init(const int* __restrict__ row_ptr,
                                                     int* __restrict__ cursor, int n) {
    int i = blockIdx.x * 256 + threadIdx.x;
    if (i < n) cursor[i] = row_ptr[i];
}

__global__ __launch_bounds__(256) void k_scatter(const int* __restrict__ ei, int E, int Et,
                                                 int* __restrict__ cursor,
                                                 int* __restrict__ src_sorted) {
    int e = blockIdx.x * 256 + threadIdx.x;
    if (e < Et) {
        int s, d;
        if (e < E) { s = ei[e]; d = ei[E + e]; } else { s = d = e - E; }
        int pos = atomicAdd(&cursor[d], 1);
        src_sorted[pos] = s;
    }
}

// ---------------- casts ----------------

__global__ __launch_bounds__(256) void k_cast_x(const float* __restrict__ x,
                                                unsigned short* __restrict__ xb,
                                                int N, int F, int kshift) {
    int i = blockIdx.x * 256 + threadIdx.x;
    if (i < (N << kshift)) {
        int n = i >> kshift, k = i & ((1 << kshift) - 1);
        float v = (k < F) ? x[n * F + k] : 0.0f;
        xb[i] = f2bf(v);
    }
}

__global__ __launch_bounds__(256) void k_cast_wt(const float* __restrict__ W,
                                                 unsigned short* __restrict__ Wt,
                                                 int K, int kshift) {
    int i = blockIdx.x * 256 + threadIdx.x;
    if (i < (256 << kshift)) {
        int n = i >> kshift, k = i & ((1 << kshift) - 1);
        Wt[i] = f2bf(k < K ? W[k * 256 + n] : 0.0f);
    }
}

// pack Wl3/Wr3 [256 x 6] into W3t [16 x 256] bf16, k-contiguous rows
__global__ __launch_bounds__(256) void k_pack_w3(const float* __restrict__ Wl,
                                                 const float* __restrict__ Wr,
                                                 unsigned short* __restrict__ W3t) {
    int i = blockIdx.x * 256 + threadIdx.x;   // < 4096
    int j = i >> 8, k = i & 255;
    float v = (j < 6) ? Wl[k * 6 + j] : ((j < 12) ? Wr[k * 6 + (j - 6)] : 0.0f);
    W3t[i] = f2bf(v);
}

// ---------------- MFMA bf16 GEMM pair: A[M x Kp] @ {Wl,Wr}^T + bias -> bf16 ----------------

#define LDST 40

__global__ __launch_bounds__(256) void k_gemm_pair_mfma(
        const unsigned short* __restrict__ A, int M, int Kp,
        const unsigned short* __restrict__ Btl, const unsigned short* __restrict__ Btr,
        const float* __restrict__ bl, const float* __restrict__ br,
        unsigned short* __restrict__ Cl, unsigned short* __restrict__ Cr) {
    __shared__ unsigned short As[128 * LDST];
    __shared__ unsigned short Bs[128 * LDST];
    const int t = threadIdx.x;
    const int wave = t >> 6, lane = t & 63;
    const int wr = wave >> 1, wc = wave & 1;
    const int l15 = lane & 15, l4 = lane >> 4;
    const int row0 = blockIdx.x * 128;
    const int mat  = blockIdx.y >> 1;
    const int col0 = (blockIdx.y & 1) * 128;
    const unsigned short* Bt = mat ? Btr : Btl;
    const float* bias        = mat ? br  : bl;
    unsigned short* C        = mat ? Cr  : Cl;

    f32x4 acc[4][4];
    #pragma unroll
    for (int a = 0; a < 4; a++)
        #pragma unroll
        for (int b = 0; b < 4; b++)
            acc[a][b] = (f32x4){0.f, 0.f, 0.f, 0.f};

    for (int k0 = 0; k0 < Kp; k0 += 32) {
        #pragma unroll
        for (int i = 0; i < 2; i++) {
            int s = t + i * 256;
            int r = s >> 2, ks = (s & 3) * 8;
            int gr = row0 + r;
            uint4 va = make_uint4(0u, 0u, 0u, 0u);
            if (gr < M) va = *(const uint4*)&A[(size_t)gr * Kp + k0 + ks];
            *(uint4*)&As[r * LDST + ks] = va;
            uint4 vb = *(const uint4*)&Bt[(size_t)(col0 + r) * Kp + k0 + ks];
            *(uint4*)&Bs[r * LDST + ks] = vb;
        }
        __syncthreads();
        bf16x8 af[4], bfr[4];
        #pragma unroll
        for (int mt = 0; mt < 4; mt++)
            af[mt] = *(const bf16x8*)&As[(wr * 64 + mt * 16 + l15) * LDST + l4 * 8];
        #pragma unroll
        for (int nt = 0; nt < 4; nt++)
            bfr[nt] = *(const bf16x8*)&Bs[(wc * 64 + nt * 16 + l15) * LDST + l4 * 8];
        #pragma unroll
        for (int mt = 0; mt < 4; mt++)
            #pragma unroll
            for (int nt = 0; nt < 4; nt++)
                acc[mt][nt] = __builtin_amdgcn_mfma_f32_16x16x32_bf16(
                    af[mt], bfr[nt], acc[mt][nt], 0, 0, 0);
        __syncthreads();
    }
    #pragma unroll
    for (int nt = 0; nt < 4; nt++) {
        int gc = col0 + wc * 64 + nt * 16 + l15;
        float bv = bias[gc];
        #pragma unroll
        for (int mt = 0; mt < 4; mt++) {
            #pragma unroll
            for (int r = 0; r < 4; r++) {
                int gr = row0 + wr * 64 + mt * 16 + l4 * 4 + r;
                if (gr < M)
                    C[(size_t)gr * 256 + gc] = f2bf(acc[mt][nt][r] + bv);
            }
        }
    }
}

// ---------------- Layer 3 transform via MFMA: h[N x 256] @ W3t[16 x 256]^T ----------------
// One wave = 16 rows; A-fragments straight from global (h is k-contiguous);
// B-fragments (the whole packed weight) hoisted to registers. Bias fused.
// Output packed l3[N x 16] bf16: j 0..5 = xl3, 6..11 = xr3.

__global__ __launch_bounds__(256) void k_gemm3_mfma(
        const unsigned short* __restrict__ h,
        const unsigned short* __restrict__ W3t,
        const float* __restrict__ bl, const float* __restrict__ br,
        unsigned short* __restrict__ l3, int N) {
    const int wave = threadIdx.x >> 6, lane = threadIdx.x & 63;
    const int l15 = lane & 15, l4 = lane >> 4;
    const int row0 = blockIdx.x * 64 + wave * 16;
    if (row0 >= N) return;

    bf16x8 bfr[8];
    #pragma unroll
    for (int ks = 0; ks < 8; ks++)
        bfr[ks] = *(const bf16x8*)&W3t[l15 * 256 + ks * 32 + l4 * 8];

    const int arow = min(row0 + l15, N - 1);
    const size_t abase = (size_t)arow * 256;
    f32x4 acc = (f32x4){0.f, 0.f, 0.f, 0.f};
    #pragma unroll
    for (int ks = 0; ks < 8; ks++) {
        bf16x8 af = *(const bf16x8*)&h[abase + ks * 32 + l4 * 8];
        acc = __builtin_amdgcn_mfma_f32_16x16x32_bf16(af, bfr[ks], acc, 0, 0, 0);
    }
    const float bv = (l15 < 6) ? bl[l15] : ((l15 < 12) ? br[l15 - 6] : 0.0f);
    #pragma unroll
    for (int r = 0; r < 4; r++) {
        int gr = row0 + l4 * 4 + r;
        if (gr < N && l15 < 12)
            l3[(size_t)gr * 16 + l15] = f2bf(acc[r] + bv);
    }
}

// ---------------- Aggregation layers 1&2 (H=4, C=64), bf16 tables, online softmax ----------------

__global__ __launch_bounds__(256) void k_agg256(const unsigned short* __restrict__ xl,
                                                const unsigned short* __restrict__ xr,
                                                const int* __restrict__ row_ptr,
                                                const int* __restrict__ src_sorted,
                                                const float* __restrict__ att,
                                                const float* __restrict__ bias,
                                                unsigned short* __restrict__ h_out, int N) {
    const int wave = threadIdx.x >> 6;
    const int lane = threadIdx.x & 63;
    const int n = blockIdx.x * 4 + wave;
    if (n >= N) return;
    const int ci = lane * 4;
    uint2 xru = *(const uint2*)&xr[(size_t)n * 256 + ci];
    const float xr0 = bf_lo(xru.x), xr1 = bf_hi(xru.x);
    const float xr2 = bf_lo(xru.y), xr3 = bf_hi(xru.y);
    const float4 at4 = *(const float4*)&att[ci];
    float4 acc = make_float4(0.f, 0.f, 0.f, 0.f);
    float m = -INFINITY, s = 0.0f;
    const int beg = row_ptr[n], end = row_ptr[n + 1];

    for (int base = beg; base < end; base += 64) {
        const int cnt = min(64, end - base);
        const int sv_r = src_sorted[base + min(lane, cnt - 1)];
        for (int j0 = 0; j0 < cnt; j0 += 4) {
            float xv[4][4];
            float lg[4];
            #pragma unroll
            for (int e = 0; e < 4; e++) {
                int sv = __shfl(sv_r, j0 + e, 64);
                uint2 u = *(const uint2*)&xl[(size_t)sv * 256 + ci];
                xv[e][0] = bf_lo(u.x); xv[e][1] = bf_hi(u.x);
                xv[e][2] = bf_lo(u.y); xv[e][3] = bf_hi(u.y);
            }
            #pragma unroll
            for (int e = 0; e < 4; e++) {
                float t0 = xv[e][0] + xr0, t1 = xv[e][1] + xr1;
                float t2 = xv[e][2] + xr2, t3 = xv[e][3] + xr3;
                t0 = t0 > 0.f ? t0 : NEG_SLOPE * t0;
                t1 = t1 > 0.f ? t1 : NEG_SLOPE * t1;
                t2 = t2 > 0.f ? t2 : NEG_SLOPE * t2;
                t3 = t3 > 0.f ? t3 : NEG_SLOPE * t3;
                lg[e] = at4.x * t0 + at4.y * t1 + at4.z * t2 + at4.w * t3;
            }
            #pragma unroll
            for (int d = 1; d < 16; d <<= 1)
                #pragma unroll
                for (int e = 0; e < 4; e++)
                    lg[e] += __shfl_xor(lg[e], d, 64);
            #pragma unroll
            for (int e = 0; e < 4; e++)
                if (j0 + e >= cnt) lg[e] = -INFINITY;
            float bm = fmaxf(fmaxf(lg[0], lg[1]), fmaxf(lg[2], lg[3]));
            float nm = fmaxf(m, bm);
            float sc = __expf(m - nm);
            acc.x *= sc; acc.y *= sc; acc.z *= sc; acc.w *= sc;
            s *= sc;
            #pragma unroll
            for (int e = 0; e < 4; e++) {
                float p = __expf(lg[e] - nm);
                s += p;
                acc.x += p * xv[e][0];
                acc.y += p * xv[e][1];
                acc.z += p * xv[e][2];
                acc.w += p * xv[e][3];
            }
            m = nm;
        }
    }
    const float inv = 1.0f / s;
    const float4 bv = *(const float4*)&bias[ci];
    float o0 = acc.x * inv + bv.x;
    float o1 = acc.y * inv + bv.y;
    float o2 = acc.z * inv + bv.z;
    float o3 = acc.w * inv + bv.w;
    o0 = o0 > 0.f ? o0 : (__expf(o0) - 1.f);
    o1 = o1 > 0.f ? o1 : (__expf(o1) - 1.f);
    o2 = o2 > 0.f ? o2 : (__expf(o2) - 1.f);
    o3 = o3 > 0.f ? o3 : (__expf(o3) - 1.f);
    ushort4 hv;
    hv.x = f2bf(o0); hv.y = f2bf(o1); hv.z = f2bf(o2); hv.w = f2bf(o3);
    *(ushort4*)&h_out[(size_t)n * 256 + ci] = hv;
}

// ---------------- Layer 3 aggregation (H=6, C=1, mean over heads), packed l3 ----------------

__global__ __launch_bounds__(64) void k_agg3(const unsigned short* __restrict__ l3,
                                             const int* __restrict__ row_ptr,
                                             const int* __restrict__ src_sorted,
                                             const float* __restrict__ att3,
                                             const float* __restrict__ bias3,
                                             float* __restrict__ out, int N) {
    int n = blockIdx.x * 64 + threadIdx.x;
    if (n >= N) return;
    // dst xr values: elements 6..11 of the packed row
    const unsigned short* pn = &l3[(size_t)n * 16];
    uint4 u1 = *(const uint4*)pn;          // j 0..7
    uint4 u2 = *(const uint4*)(pn + 8);    // j 8..15
    float xrv[6];
    xrv[0] = bf_lo(u1.w); xrv[1] = bf_hi(u1.w);
    xrv[2] = bf_lo(u2.x); xrv[3] = bf_hi(u2.x);
    xrv[4] = bf_lo(u2.y); xrv[5] = bf_hi(u2.y);
    float attv[6], m[6], s[6], acc[6];
    #pragma unroll
    for (int j = 0; j < 6; j++) {
        attv[j] = att3[j];
        m[j] = -INFINITY; s[j] = 0.0f; acc[j] = 0.0f;
    }
    int beg = row_ptr[n], end = row_ptr[n + 1];
    for (int idx = beg; idx < end; idx++) {
        int sv = src_sorted[idx];
        uint4 u = *(const uint4*)&l3[(size_t)sv * 16];   // xl j 0..5 in one load
        float xlv[6];
        xlv[0] = bf_lo(u.x); xlv[1] = bf_hi(u.x);
        xlv[2] = bf_lo(u.y); xlv[3] = bf_hi(u.y);
        xlv[4] = bf_lo(u.z); xlv[5] = bf_hi(u.z);
        #pragma unroll
        for (int j = 0; j < 6; j++) {
            float tt = xlv[j] + xrv[j];
            float lr = tt > 0.0f ? tt : NEG_SLOPE * tt;
            float logit = attv[j] * lr;
            float nm = fmaxf(m[j], logit);
            float sc = __expf(m[j] - nm);
            float p  = __expf(logit - nm);
            acc[j] = acc[j] * sc + p * xlv[j];
            s[j]   = s[j] * sc + p;
            m[j]   = nm;
        }
    }
    float o = 0.0f;
    #pragma unroll
    for (int j = 0; j < 6; j++) o += acc[j] / s[j];
    out[n] = o * (1.0f / 6.0f) + bias3[0];
}

// ---------------- launch ----------------

extern "C" void kernel_launch(void* const* d_in, const int* in_sizes, int n_in,
                              void* d_out, int out_size, void* d_ws, size_t ws_size,
                              hipStream_t stream) {
    const float* x    = (const float*)d_in[0];
    const int*   ei   = (const int*)  d_in[1];
    const float* Wl1  = (const float*)d_in[2];
    const float* bl1  = (const float*)d_in[3];
    const float* Wr1  = (const float*)d_in[4];
    const float* br1  = (const float*)d_in[5];
    const float* att1 = (const float*)d_in[6];
    const float* bias1= (const float*)d_in[7];
    const float* Wl2  = (const float*)d_in[8];
    const float* bl2  = (const float*)d_in[9];
    const float* Wr2  = (const float*)d_in[10];
    const float* br2  = (const float*)d_in[11];
    const float* att2 = (const float*)d_in[12];
    const float* bias2= (const float*)d_in[13];
    const float* Wl3  = (const float*)d_in[14];
    const float* bl3  = (const float*)d_in[15];
    const float* Wr3  = (const float*)d_in[16];
    const float* br3  = (const float*)d_in[17];
    const float* att3 = (const float*)d_in[18];
    const float* bias3= (const float*)d_in[19];

    const int F  = in_sizes[2] / 256;   // 58
    const int N  = in_sizes[0] / F;     // 50000
    const int E  = in_sizes[1] / 2;     // 500000
    const int Et = E + N;

    char* ws = (char*)d_ws;
    size_t off = 0;
    auto carve = [&](size_t bytes) -> char* {
        char* p = ws + off;
        off = (off + bytes + 255) & ~(size_t)255;
        return p;
    };
    unsigned short* xb   = (unsigned short*)carve((size_t)N * 64 * 2);
    unsigned short* xlb  = (unsigned short*)carve((size_t)N * 256 * 2);
    unsigned short* xrb  = (unsigned short*)carve((size_t)N * 256 * 2);
    unsigned short* hb   = (unsigned short*)carve((size_t)N * 256 * 2);
    unsigned short* wtl1 = (unsigned short*)carve(256 * 64 * 2);
    unsigned short* wtr1 = (unsigned short*)carve(256 * 64 * 2);
    unsigned short* wtl2 = (unsigned short*)carve(256 * 256 * 2);
    unsigned short* wtr2 = (unsigned short*)carve(256 * 256 * 2);
    unsigned short* w3t  = (unsigned short*)carve(16 * 256 * 2);
    unsigned short* l3   = (unsigned short*)carve((size_t)N * 16 * 2);
    int* cnt        = (int*)carve((size_t)N * 4);
    int* row_ptr    = (int*)carve((size_t)(N + 1) * 4);
    int* cursor     = (int*)carve((size_t)N * 4);
    int* src_sorted = (int*)carve((size_t)Et * 4);
    int* bsums      = (int*)carve(1024 * 4);

    const int gN  = (N + 255) / 256;
    const int gEt = (Et + 255) / 256;
    const int gW  = (N + 3) / 4;

    // --- CSR build ---
    hipMemsetAsync(cnt, 0, (size_t)N * 4, stream);
    k_count<<<gEt, 256, 0, stream>>>(ei, E, Et, cnt);
    k_scan_block<<<gN, 256, 0, stream>>>(cnt, row_ptr, bsums, N);
    k_scan_bsums<<<1, 256, 0, stream>>>(bsums, gN);
    k_scan_add<<<gN, 256, 0, stream>>>(row_ptr, bsums, N, Et);
    k_cursor_init<<<gN, 256, 0, stream>>>(row_ptr, cursor, N);
    k_scatter<<<gEt, 256, 0, stream>>>(ei, E, Et, cursor, src_sorted);

    // --- casts / packs ---
    k_cast_x<<<((N << 6) + 255) / 256, 256, 0, stream>>>(x, xb, N, F, 6);
    k_cast_wt<<<(256 << 6) / 256, 256, 0, stream>>>(Wl1, wtl1, F, 6);
    k_cast_wt<<<(256 << 6) / 256, 256, 0, stream>>>(Wr1, wtr1, F, 6);
    k_cast_wt<<<(256 << 8) / 256, 256, 0, stream>>>(Wl2, wtl2, 256, 8);
    k_cast_wt<<<(256 << 8) / 256, 256, 0, stream>>>(Wr2, wtr2, 256, 8);
    k_pack_w3<<<16, 256, 0, stream>>>(Wl3, Wr3, w3t);

    dim3 gemm_grid((N + 127) / 128, 4);

    // --- Layer 1 ---
    k_gemm_pair_mfma<<<gemm_grid, 256, 0, stream>>>(xb, N, 64, wtl1, wtr1, bl1, br1, xlb, xrb);
    k_agg256<<<gW, 256, 0, stream>>>(xlb, xrb, row_ptr, src_sorted, att1, bias1, hb, N);

    // --- Layer 2 ---
    k_gemm_pair_mfma<<<gemm_grid, 256, 0, stream>>>(hb, N, 256, wtl2, wtr2, bl2, br2, xlb, xrb);
    k_agg256<<<gW, 256, 0, stream>>>(xlb, xrb, row_ptr, src_sorted, att2, bias2, hb, N);

    // --- Layer 3 ---
    k_gemm3_mfma<<<(N + 63) / 64, 256, 0, stream>>>(hb, w3t, bl3, br3, l3, N);
    k_agg3<<<(N + 63) / 64, 64, 0, stream>>>(l3, row_ptr, src_sorted, att3, bias3,
                                             (float*)d_out, N);
}

// Round 5
// 393.002 us; speedup vs baseline: 2.2964x; 1.0261x over previous
//
#include <hip/hip_runtime.h>
#include <math.h>

#define NEG_SLOPE 0.2f

typedef __attribute__((ext_vector_type(8))) short bf16x8;
typedef __attribute__((ext_vector_type(4))) float f32x4;

__device__ inline unsigned short f2bf(float f) {
    unsigned u = __float_as_uint(f);
    u += 0x7fffu + ((u >> 16) & 1u);          // round-to-nearest-even
    return (unsigned short)(u >> 16);
}
__device__ inline float bf_lo(unsigned u) { return __uint_as_float(u << 16); }
__device__ inline float bf_hi(unsigned u) { return __uint_as_float(u & 0xffff0000u); }

// ---------------- CSR build ----------------

__global__ __launch_bounds__(256) void k_count(const int* __restrict__ ei, int E, int Et,
                                               int* __restrict__ cnt) {
    int e = blockIdx.x * 256 + threadIdx.x;
    if (e < Et) {
        int d = (e < E) ? ei[E + e] : (e - E);
        atomicAdd(&cnt[d], 1);
    }
}

__global__ __launch_bounds__(256) void k_scan_block(const int* __restrict__ cnt,
                                                    int* __restrict__ out,
                                                    int* __restrict__ bsums, int n) {
    __shared__ int tmp[256];
    int t = threadIdx.x;
    int i = blockIdx.x * 256 + t;
    int v = (i < n) ? cnt[i] : 0;
    tmp[t] = v;
    __syncthreads();
    for (int d = 1; d < 256; d <<= 1) {
        int add = (t >= d) ? tmp[t - d] : 0;
        __syncthreads();
        tmp[t] += add;
        __syncthreads();
    }
    if (i < n) out[i] = tmp[t] - v;
    if (t == 255) bsums[blockIdx.x] = tmp[t];
}

__global__ __launch_bounds__(256) void k_scan_bsums(int* bsums, int nb) {
    __shared__ int tmp[256];
    int t = threadIdx.x;
    int v = (t < nb) ? bsums[t] : 0;
    tmp[t] = v;
    __syncthreads();
    for (int d = 1; d < 256; d <<= 1) {
        int add = (t >= d) ? tmp[t - d] : 0;
        __syncthreads();
        tmp[t] += add;
        __syncthreads();
    }
    if (t < nb) bsums[t] = tmp[t] - v;
}

// scan_add with cursor-init fused
__global__ __launch_bounds__(256) void k_scan_add(int* __restrict__ out,
                                                  const int* __restrict__ bsums,
                                                  int* __restrict__ cursor,
                                                  int n, int total) {
    int i = blockIdx.x * 256 + threadIdx.x;
    if (i < n) {
        int v = out[i] + bsums[blockIdx.x];
        out[i] = v;
        cursor[i] = v;
    }
    if (i == 0) out[n] = total;
}

__global__ __launch_bounds__(256) void k_scatter(const int* __restrict__ ei, int E, int Et,
                                                 int* __restrict__ cursor,
                                                 int* __restrict__ src_sorted) {
    int e = blockIdx.x * 256 + threadIdx.x;
    if (e < Et) {
        int s, d;
        if (e < E) { s = ei[e]; d = ei[E + e]; } else { s = d = e - E; }
        int pos = atomicAdd(&cursor[d], 1);
        src_sorted[pos] = s;
    }
}

// ---------------- casts (merged) ----------------

__global__ __launch_bounds__(256) void k_cast_x(const float* __restrict__ x,
                                                unsigned short* __restrict__ xb,
                                                int N, int F, int kshift) {
    int i = blockIdx.x * 256 + threadIdx.x;
    if (i < (N << kshift)) {
        int n = i >> kshift, k = i & ((1 << kshift) - 1);
        float v = (k < F) ? x[n * F + k] : 0.0f;
        xb[i] = f2bf(v);
    }
}

// all weight casts/packs in one launch:
// [0,16384)       wtl1 [256 x 64]   from Wl1 [F x 256] (k-pad to 64)
// [16384,32768)   wtr1
// [32768,98304)   wtl2 [256 x 256]  from Wl2 [256 x 256]
// [98304,163840)  wtr2
// [163840,167936) w3t  [16 x 256]   rows 0-5 Wl3^T, 6-11 Wr3^T, 12-15 zero
__global__ __launch_bounds__(256) void k_cast_w_all(
        const float* __restrict__ Wl1, const float* __restrict__ Wr1,
        const float* __restrict__ Wl2, const float* __restrict__ Wr2,
        const float* __restrict__ Wl3, const float* __restrict__ Wr3,
        unsigned short* __restrict__ wtl1, unsigned short* __restrict__ wtr1,
        unsigned short* __restrict__ wtl2, unsigned short* __restrict__ wtr2,
        unsigned short* __restrict__ w3t, int F) {
    int i = blockIdx.x * 256 + threadIdx.x;
    if (i < 32768) {
        const float* W = (i < 16384) ? Wl1 : Wr1;
        unsigned short* O = (i < 16384) ? wtl1 : wtr1;
        int loc = i & 16383;
        int n = loc >> 6, k = loc & 63;
        O[loc] = f2bf(k < F ? W[k * 256 + n] : 0.0f);
    } else if (i < 163840) {
        int seg = i - 32768;
        const float* W = (seg < 65536) ? Wl2 : Wr2;
        unsigned short* O = (seg < 65536) ? wtl2 : wtr2;
        int loc = seg & 65535;
        int n = loc >> 8, k = loc & 255;
        O[loc] = f2bf(W[k * 256 + n]);
    } else if (i < 167936) {
        int loc = i - 163840;
        int j = loc >> 8, k = loc & 255;
        float v = (j < 6) ? Wl3[k * 6 + j] : ((j < 12) ? Wr3[k * 6 + (j - 6)] : 0.0f);
        w3t[loc] = f2bf(v);
    }
}

// ---------------- MFMA bf16 GEMM pair: A[M x Kp] @ {Wl,Wr}^T + bias -> bf16 ----------------
// Block = 128 rows x 128-col half of BOTH matrices (grid y = 2). A tile loaded once
// serves 2 matrices (halves A traffic vs matrix-split grid). 2x2 wave grid, per wave
// 4x4 mfma tiles x 2 matrices = 32 MFMA per 12 ds_read_b128 per k-step.

#define LDST 40

__global__ __launch_bounds__(256, 2) void k_gemm_pair_mfma(
        const unsigned short* __restrict__ A, int M, int Kp,
        const unsigned short* __restrict__ Btl, const unsigned short* __restrict__ Btr,
        const float* __restrict__ bl, const float* __restrict__ br,
        unsigned short* __restrict__ Cl, unsigned short* __restrict__ Cr) {
    __shared__ unsigned short As[128 * LDST];
    __shared__ unsigned short Bls[128 * LDST];
    __shared__ unsigned short Brs[128 * LDST];
    const int t = threadIdx.x;
    const int wave = t >> 6, lane = t & 63;
    const int wr = wave >> 1, wc = wave & 1;
    const int l15 = lane & 15, l4 = lane >> 4;
    const int row0 = blockIdx.x * 128;
    const int col0 = blockIdx.y * 128;

    f32x4 accl[4][4], accr[4][4];
    #pragma unroll
    for (int a = 0; a < 4; a++)
        #pragma unroll
        for (int b = 0; b < 4; b++) {
            accl[a][b] = (f32x4){0.f, 0.f, 0.f, 0.f};
            accr[a][b] = (f32x4){0.f, 0.f, 0.f, 0.f};
        }

    for (int k0 = 0; k0 < Kp; k0 += 32) {
        #pragma unroll
        for (int i = 0; i < 2; i++) {
            int s = t + i * 256;
            int r = s >> 2, ks = (s & 3) * 8;
            int gr = row0 + r;
            uint4 va = make_uint4(0u, 0u, 0u, 0u);
            if (gr < M) va = *(const uint4*)&A[(size_t)gr * Kp + k0 + ks];
            *(uint4*)&As[r * LDST + ks] = va;
            *(uint4*)&Bls[r * LDST + ks] = *(const uint4*)&Btl[(size_t)(col0 + r) * Kp + k0 + ks];
            *(uint4*)&Brs[r * LDST + ks] = *(const uint4*)&Btr[(size_t)(col0 + r) * Kp + k0 + ks];
        }
        __syncthreads();
        bf16x8 af[4], bfl[4], bfr[4];
        #pragma unroll
        for (int mt = 0; mt < 4; mt++)
            af[mt] = *(const bf16x8*)&As[(wr * 64 + mt * 16 + l15) * LDST + l4 * 8];
        #pragma unroll
        for (int nt = 0; nt < 4; nt++) {
            bfl[nt] = *(const bf16x8*)&Bls[(wc * 64 + nt * 16 + l15) * LDST + l4 * 8];
            bfr[nt] = *(const bf16x8*)&Brs[(wc * 64 + nt * 16 + l15) * LDST + l4 * 8];
        }
        #pragma unroll
        for (int mt = 0; mt < 4; mt++)
            #pragma unroll
            for (int nt = 0; nt < 4; nt++) {
                accl[mt][nt] = __builtin_amdgcn_mfma_f32_16x16x32_bf16(
                    af[mt], bfl[nt], accl[mt][nt], 0, 0, 0);
                accr[mt][nt] = __builtin_amdgcn_mfma_f32_16x16x32_bf16(
                    af[mt], bfr[nt], accr[mt][nt], 0, 0, 0);
            }
        __syncthreads();
    }
    #pragma unroll
    for (int nt = 0; nt < 4; nt++) {
        int gc = col0 + wc * 64 + nt * 16 + l15;
        float bvl = bl[gc], bvr = br[gc];
        #pragma unroll
        for (int mt = 0; mt < 4; mt++) {
            #pragma unroll
            for (int r = 0; r < 4; r++) {
                int gr = row0 + wr * 64 + mt * 16 + l4 * 4 + r;
                if (gr < M) {
                    Cl[(size_t)gr * 256 + gc] = f2bf(accl[mt][nt][r] + bvl);
                    Cr[(size_t)gr * 256 + gc] = f2bf(accr[mt][nt][r] + bvr);
                }
            }
        }
    }
}

// ---------------- Layer 3 transform via MFMA ----------------

__global__ __launch_bounds__(256) void k_gemm3_mfma(
        const unsigned short* __restrict__ h,
        const unsigned short* __restrict__ W3t,
        const float* __restrict__ bl, const float* __restrict__ br,
        unsigned short* __restrict__ l3, int N) {
    const int wave = threadIdx.x >> 6, lane = threadIdx.x & 63;
    const int l15 = lane & 15, l4 = lane >> 4;
    const int row0 = blockIdx.x * 64 + wave * 16;
    if (row0 >= N) return;

    bf16x8 bfr[8];
    #pragma unroll
    for (int ks = 0; ks < 8; ks++)
        bfr[ks] = *(const bf16x8*)&W3t[l15 * 256 + ks * 32 + l4 * 8];

    const int arow = min(row0 + l15, N - 1);
    const size_t abase = (size_t)arow * 256;
    f32x4 acc = (f32x4){0.f, 0.f, 0.f, 0.f};
    #pragma unroll
    for (int ks = 0; ks < 8; ks++) {
        bf16x8 af = *(const bf16x8*)&h[abase + ks * 32 + l4 * 8];
        acc = __builtin_amdgcn_mfma_f32_16x16x32_bf16(af, bfr[ks], acc, 0, 0, 0);
    }
    const float bv = (l15 < 6) ? bl[l15] : ((l15 < 12) ? br[l15 - 6] : 0.0f);
    #pragma unroll
    for (int r = 0; r < 4; r++) {
        int gr = row0 + l4 * 4 + r;
        if (gr < N && l15 < 12)
            l3[(size_t)gr * 16 + l15] = f2bf(acc[r] + bv);
    }
}

// ---------------- Aggregation layers 1&2 (H=4, C=64), online softmax ----------------
// Wave-per-node; lane owns 4 contiguous channels. Hot loop: unmasked batches of 8
// edges per rescale; masked 4-wide tail. leaky(t) = max(t, 0.2t).

__global__ __launch_bounds__(256) void k_agg256(const unsigned short* __restrict__ xl,
                                                const unsigned short* __restrict__ xr,
                                                const int* __restrict__ row_ptr,
                                                const int* __restrict__ src_sorted,
                                                const float* __restrict__ att,
                                                const float* __restrict__ bias,
                                                unsigned short* __restrict__ h_out, int N) {
    const int wave = threadIdx.x >> 6;
    const int lane = threadIdx.x & 63;
    const int n = blockIdx.x * 4 + wave;
    if (n >= N) return;
    const int ci = lane * 4;
    const uint2* __restrict__ xl2 = (const uint2*)xl;   // row = 64 uint2
    uint2 xru = *(const uint2*)&xr[(size_t)n * 256 + ci];
    const float xr0 = bf_lo(xru.x), xr1 = bf_hi(xru.x);
    const float xr2 = bf_lo(xru.y), xr3 = bf_hi(xru.y);
    const float4 at4 = *(const float4*)&att[ci];
    float a0 = 0.f, a1 = 0.f, a2 = 0.f, a3 = 0.f;
    float m = -INFINITY, s = 0.0f;
    const int beg = row_ptr[n], end = row_ptr[n + 1];

    for (int base = beg; base < end; base += 64) {
        const int cnt = min(64, end - base);
        const int sv_r = src_sorted[base + min(lane, cnt - 1)];
        int j0 = 0;
        // ---- unmasked batches of 8 ----
        for (; j0 + 8 <= cnt; j0 += 8) {
            uint2 u[8];
            #pragma unroll
            for (int e = 0; e < 8; e++) {
                int sv = __shfl(sv_r, j0 + e, 64);
                u[e] = xl2[(size_t)sv * 64 + lane];
            }
            float xf[8][4], lg[8];
            #pragma unroll
            for (int e = 0; e < 8; e++) {
                xf[e][0] = bf_lo(u[e].x); xf[e][1] = bf_hi(u[e].x);
                xf[e][2] = bf_lo(u[e].y); xf[e][3] = bf_hi(u[e].y);
                float t0 = xf[e][0] + xr0, t1 = xf[e][1] + xr1;
                float t2 = xf[e][2] + xr2, t3 = xf[e][3] + xr3;
                t0 = fmaxf(t0, NEG_SLOPE * t0); t1 = fmaxf(t1, NEG_SLOPE * t1);
                t2 = fmaxf(t2, NEG_SLOPE * t2); t3 = fmaxf(t3, NEG_SLOPE * t3);
                lg[e] = at4.x * t0 + at4.y * t1 + at4.z * t2 + at4.w * t3;
            }
            #pragma unroll
            for (int d = 1; d < 16; d <<= 1)
                #pragma unroll
                for (int e = 0; e < 8; e++)
                    lg[e] += __shfl_xor(lg[e], d, 64);
            float bm = fmaxf(fmaxf(fmaxf(lg[0], lg[1]), fmaxf(lg[2], lg[3])),
                             fmaxf(fmaxf(lg[4], lg[5]), fmaxf(lg[6], lg[7])));
            float nm = fmaxf(m, bm);
            float sc = __expf(m - nm);
            a0 *= sc; a1 *= sc; a2 *= sc; a3 *= sc;
            float p[8];
            #pragma unroll
            for (int e = 0; e < 8; e++) p[e] = __expf(lg[e] - nm);
            #pragma unroll
            for (int e = 0; e < 8; e++) {
                a0 += p[e] * xf[e][0]; a1 += p[e] * xf[e][1];
                a2 += p[e] * xf[e][2]; a3 += p[e] * xf[e][3];
            }
            float ps = ((p[0] + p[1]) + (p[2] + p[3])) + ((p[4] + p[5]) + (p[6] + p[7]));
            s = s * sc + ps;
            m = nm;
        }
        // ---- masked 4-wide tail ----
        for (; j0 < cnt; j0 += 4) {
            uint2 u[4];
            #pragma unroll
            for (int e = 0; e < 4; e++) {
                int sv = __shfl(sv_r, min(j0 + e, cnt - 1), 64);
                u[e] = xl2[(size_t)sv * 64 + lane];
            }
            float xf[4][4], lg[4];
            #pragma unroll
            for (int e = 0; e < 4; e++) {
                xf[e][0] = bf_lo(u[e].x); xf[e][1] = bf_hi(u[e].x);
                xf[e][2] = bf_lo(u[e].y); xf[e][3] = bf_hi(u[e].y);
                float t0 = xf[e][0] + xr0, t1 = xf[e][1] + xr1;
                float t2 = xf[e][2] + xr2, t3 = xf[e][3] + xr3;
                t0 = fmaxf(t0, NEG_SLOPE * t0); t1 = fmaxf(t1, NEG_SLOPE * t1);
                t2 = fmaxf(t2, NEG_SLOPE * t2); t3 = fmaxf(t3, NEG_SLOPE * t3);
                lg[e] = at4.x * t0 + at4.y * t1 + at4.z * t2 + at4.w * t3;
            }
            #pragma unroll
            for (int d = 1; d < 16; d <<= 1)
                #pragma unroll
                for (int e = 0; e < 4; e++)
                    lg[e] += __shfl_xor(lg[e], d, 64);
            #pragma unroll
            for (int e = 0; e < 4; e++)
                if (j0 + e >= cnt) lg[e] = -INFINITY;
            float bm = fmaxf(fmaxf(lg[0], lg[1]), fmaxf(lg[2], lg[3]));
            float nm = fmaxf(m, bm);
            float sc = __expf(m - nm);
            a0 *= sc; a1 *= sc; a2 *= sc; a3 *= sc;
            float p[4];
            #pragma unroll
            for (int e = 0; e < 4; e++) p[e] = __expf(lg[e] - nm);
            #pragma unroll
            for (int e = 0; e < 4; e++) {
                a0 += p[e] * xf[e][0]; a1 += p[e] * xf[e][1];
                a2 += p[e] * xf[e][2]; a3 += p[e] * xf[e][3];
            }
            s = s * sc + ((p[0] + p[1]) + (p[2] + p[3]));
            m = nm;
        }
    }
    const float inv = 1.0f / s;
    const float4 bv = *(const float4*)&bias[ci];
    float o0 = a0 * inv + bv.x;
    float o1 = a1 * inv + bv.y;
    float o2 = a2 * inv + bv.z;
    float o3 = a3 * inv + bv.w;
    o0 = o0 > 0.f ? o0 : (__expf(o0) - 1.f);
    o1 = o1 > 0.f ? o1 : (__expf(o1) - 1.f);
    o2 = o2 > 0.f ? o2 : (__expf(o2) - 1.f);
    o3 = o3 > 0.f ? o3 : (__expf(o3) - 1.f);
    ushort4 hv;
    hv.x = f2bf(o0); hv.y = f2bf(o1); hv.z = f2bf(o2); hv.w = f2bf(o3);
    *(ushort4*)&h_out[(size_t)n * 256 + ci] = hv;
}

// ---------------- Layer 3 aggregation (H=6, C=1, mean over heads), packed l3 ----------------

__global__ __launch_bounds__(64) void k_agg3(const unsigned short* __restrict__ l3,
                                             const int* __restrict__ row_ptr,
                                             const int* __restrict__ src_sorted,
                                             const float* __restrict__ att3,
                                             const float* __restrict__ bias3,
                                             float* __restrict__ out, int N) {
    int n = blockIdx.x * 64 + threadIdx.x;
    if (n >= N) return;
    const unsigned short* pn = &l3[(size_t)n * 16];
    uint4 u1 = *(const uint4*)pn;
    uint4 u2 = *(const uint4*)(pn + 8);
    float xrv[6];
    xrv[0] = bf_lo(u1.w); xrv[1] = bf_hi(u1.w);
    xrv[2] = bf_lo(u2.x); xrv[3] = bf_hi(u2.x);
    xrv[4] = bf_lo(u2.y); xrv[5] = bf_hi(u2.y);
    float attv[6], m[6], s[6], acc[6];
    #pragma unroll
    for (int j = 0; j < 6; j++) {
        attv[j] = att3[j];
        m[j] = -INFINITY; s[j] = 0.0f; acc[j] = 0.0f;
    }
    int beg = row_ptr[n], end = row_ptr[n + 1];
    for (int idx = beg; idx < end; idx++) {
        int sv = src_sorted[idx];
        uint4 u = *(const uint4*)&l3[(size_t)sv * 16];
        float xlv[6];
        xlv[0] = bf_lo(u.x); xlv[1] = bf_hi(u.x);
        xlv[2] = bf_lo(u.y); xlv[3] = bf_hi(u.y);
        xlv[4] = bf_lo(u.z); xlv[5] = bf_hi(u.z);
        #pragma unroll
        for (int j = 0; j < 6; j++) {
            float tt = xlv[j] + xrv[j];
            float lr = fmaxf(tt, NEG_SLOPE * tt);
            float logit = attv[j] * lr;
            float nm = fmaxf(m[j], logit);
            float sc = __expf(m[j] - nm);
            float p  = __expf(logit - nm);
            acc[j] = acc[j] * sc + p * xlv[j];
            s[j]   = s[j] * sc + p;
            m[j]   = nm;
        }
    }
    float o = 0.0f;
    #pragma unroll
    for (int j = 0; j < 6; j++) o += acc[j] / s[j];
    out[n] = o * (1.0f / 6.0f) + bias3[0];
}

// ---------------- launch ----------------

extern "C" void kernel_launch(void* const* d_in, const int* in_sizes, int n_in,
                              void* d_out, int out_size, void* d_ws, size_t ws_size,
                              hipStream_t stream) {
    const float* x    = (const float*)d_in[0];
    const int*   ei   = (const int*)  d_in[1];
    const float* Wl1  = (const float*)d_in[2];
    const float* bl1  = (const float*)d_in[3];
    const float* Wr1  = (const float*)d_in[4];
    const float* br1  = (const float*)d_in[5];
    const float* att1 = (const float*)d_in[6];
    const float* bias1= (const float*)d_in[7];
    const float* Wl2  = (const float*)d_in[8];
    const float* bl2  = (const float*)d_in[9];
    const float* Wr2  = (const float*)d_in[10];
    const float* br2  = (const float*)d_in[11];
    const float* att2 = (const float*)d_in[12];
    const float* bias2= (const float*)d_in[13];
    const float* Wl3  = (const float*)d_in[14];
    const float* bl3  = (const float*)d_in[15];
    const float* Wr3  = (const float*)d_in[16];
    const float* br3  = (const float*)d_in[17];
    const float* att3 = (const float*)d_in[18];
    const float* bias3= (const float*)d_in[19];

    const int F  = in_sizes[2] / 256;   // 58
    const int N  = in_sizes[0] / F;     // 50000
    const int E  = in_sizes[1] / 2;     // 500000
    const int Et = E + N;

    char* ws = (char*)d_ws;
    size_t off = 0;
    auto carve = [&](size_t bytes) -> char* {
        char* p = ws + off;
        off = (off + bytes + 255) & ~(size_t)255;
        return p;
    };
    unsigned short* xb   = (unsigned short*)carve((size_t)N * 64 * 2);
    unsigned short* xlb  = (unsigned short*)carve((size_t)N * 256 * 2);
    unsigned short* xrb  = (unsigned short*)carve((size_t)N * 256 * 2);
    unsigned short* hb   = (unsigned short*)carve((size_t)N * 256 * 2);
    unsigned short* wtl1 = (unsigned short*)carve(256 * 64 * 2);
    unsigned short* wtr1 = (unsigned short*)carve(256 * 64 * 2);
    unsigned short* wtl2 = (unsigned short*)carve(256 * 256 * 2);
    unsigned short* wtr2 = (unsigned short*)carve(256 * 256 * 2);
    unsigned short* w3t  = (unsigned short*)carve(16 * 256 * 2);
    unsigned short* l3   = (unsigned short*)carve((size_t)N * 16 * 2);
    int* cnt        = (int*)carve((size_t)N * 4);
    int* row_ptr    = (int*)carve((size_t)(N + 1) * 4);
    int* cursor     = (int*)carve((size_t)N * 4);
    int* src_sorted = (int*)carve((size_t)Et * 4);
    int* bsums      = (int*)carve(1024 * 4);

    const int gN  = (N + 255) / 256;
    const int gEt = (Et + 255) / 256;
    const int gW  = (N + 3) / 4;

    // --- CSR build ---
    hipMemsetAsync(cnt, 0, (size_t)N * 4, stream);
    k_count<<<gEt, 256, 0, stream>>>(ei, E, Et, cnt);
    k_scan_block<<<gN, 256, 0, stream>>>(cnt, row_ptr, bsums, N);
    k_scan_bsums<<<1, 256, 0, stream>>>(bsums, gN);
    k_scan_add<<<gN, 256, 0, stream>>>(row_ptr, bsums, cursor, N, Et);
    k_scatter<<<gEt, 256, 0, stream>>>(ei, E, Et, cursor, src_sorted);

    // --- casts / packs ---
    k_cast_x<<<((N << 6) + 255) / 256, 256, 0, stream>>>(x, xb, N, F, 6);
    k_cast_w_all<<<656, 256, 0, stream>>>(Wl1, Wr1, Wl2, Wr2, Wl3, Wr3,
                                          wtl1, wtr1, wtl2, wtr2, w3t, F);

    dim3 gemm_grid((N + 127) / 128, 2);

    // --- Layer 1 ---
    k_gemm_pair_mfma<<<gemm_grid, 256, 0, stream>>>(xb, N, 64, wtl1, wtr1, bl1, br1, xlb, xrb);
    k_agg256<<<gW, 256, 0, stream>>>(xlb, xrb, row_ptr, src_sorted, att1, bias1, hb, N);

    // --- Layer 2 ---
    k_gemm_pair_mfma<<<gemm_grid, 256, 0, stream>>>(hb, N, 256, wtl2, wtr2, bl2, br2, xlb, xrb);
    k_agg256<<<gW, 256, 0, stream>>>(xlb, xrb, row_ptr, src_sorted, att2, bias2, hb, N);

    // --- Layer 3 ---
    k_gemm3_mfma<<<(N + 63) / 64, 256, 0, stream>>>(hb, w3t, bl3, br3, l3, N);
    k_agg3<<<(N + 63) / 64, 64, 0, stream>>>(l3, row_ptr, src_sorted, att3, bias3,
                                             (float*)d_out, N);
}

// Round 6
// 371.139 us; speedup vs baseline: 2.4317x; 1.0589x over previous
//
#include <hip/hip_runtime.h>
#include <math.h>

#define NEG_SLOPE 0.2f

typedef __attribute__((ext_vector_type(2))) _Float16 h2;
typedef __attribute__((ext_vector_type(4))) _Float16 h4;
typedef __attribute__((ext_vector_type(8))) _Float16 f16x8;
typedef __attribute__((ext_vector_type(4))) float f32x4;

// ---------------- CSR build ----------------

__global__ __launch_bounds__(256) void k_count(const int* __restrict__ ei, int E, int Et,
                                               int* __restrict__ cnt) {
    int e = blockIdx.x * 256 + threadIdx.x;
    if (e < Et) {
        int d = (e < E) ? ei[E + e] : (e - E);
        atomicAdd(&cnt[d], 1);
    }
}

__global__ __launch_bounds__(256) void k_scan_block(const int* __restrict__ cnt,
                                                    int* __restrict__ out,
                                                    int* __restrict__ bsums, int n) {
    __shared__ int tmp[256];
    int t = threadIdx.x;
    int i = blockIdx.x * 256 + t;
    int v = (i < n) ? cnt[i] : 0;
    tmp[t] = v;
    __syncthreads();
    for (int d = 1; d < 256; d <<= 1) {
        int add = (t >= d) ? tmp[t - d] : 0;
        __syncthreads();
        tmp[t] += add;
        __syncthreads();
    }
    if (i < n) out[i] = tmp[t] - v;
    if (t == 255) bsums[blockIdx.x] = tmp[t];
}

__global__ __launch_bounds__(256) void k_scan_bsums(int* bsums, int nb) {
    __shared__ int tmp[256];
    int t = threadIdx.x;
    int v = (t < nb) ? bsums[t] : 0;
    tmp[t] = v;
    __syncthreads();
    for (int d = 1; d < 256; d <<= 1) {
        int add = (t >= d) ? tmp[t - d] : 0;
        __syncthreads();
        tmp[t] += add;
        __syncthreads();
    }
    if (t < nb) bsums[t] = tmp[t] - v;
}

__global__ __launch_bounds__(256) void k_scan_add(int* __restrict__ out,
                                                  const int* __restrict__ bsums,
                                                  int* __restrict__ cursor,
                                                  int n, int total) {
    int i = blockIdx.x * 256 + threadIdx.x;
    if (i < n) {
        int v = out[i] + bsums[blockIdx.x];
        out[i] = v;
        cursor[i] = v;
    }
    if (i == 0) out[n] = total;
}

__global__ __launch_bounds__(256) void k_scatter(const int* __restrict__ ei, int E, int Et,
                                                 int* __restrict__ cursor,
                                                 int* __restrict__ src_sorted) {
    int e = blockIdx.x * 256 + threadIdx.x;
    if (e < Et) {
        int s, d;
        if (e < E) { s = ei[e]; d = ei[E + e]; } else { s = d = e - E; }
        int pos = atomicAdd(&cursor[d], 1);
        src_sorted[pos] = s;
    }
}

// ---------------- casts ----------------

__global__ __launch_bounds__(256) void k_cast_x(const float* __restrict__ x,
                                                _Float16* __restrict__ xb,
                                                int N, int F, int kshift) {
    int i = blockIdx.x * 256 + threadIdx.x;
    if (i < (N << kshift)) {
        int n = i >> kshift, k = i & ((1 << kshift) - 1);
        float v = (k < F) ? x[n * F + k] : 0.0f;
        xb[i] = (_Float16)v;
    }
}

// all weight casts/packs in one launch (fp16, transposed, k-padded)
__global__ __launch_bounds__(256) void k_cast_w_all(
        const float* __restrict__ Wl1, const float* __restrict__ Wr1,
        const float* __restrict__ Wl2, const float* __restrict__ Wr2,
        const float* __restrict__ Wl3, const float* __restrict__ Wr3,
        _Float16* __restrict__ wtl1, _Float16* __restrict__ wtr1,
        _Float16* __restrict__ wtl2, _Float16* __restrict__ wtr2,
        _Float16* __restrict__ w3t, int F) {
    int i = blockIdx.x * 256 + threadIdx.x;
    if (i < 32768) {
        const float* W = (i < 16384) ? Wl1 : Wr1;
        _Float16* O = (i < 16384) ? wtl1 : wtr1;
        int loc = i & 16383;
        int n = loc >> 6, k = loc & 63;
        O[loc] = (_Float16)(k < F ? W[k * 256 + n] : 0.0f);
    } else if (i < 163840) {
        int seg = i - 32768;
        const float* W = (seg < 65536) ? Wl2 : Wr2;
        _Float16* O = (seg < 65536) ? wtl2 : wtr2;
        int loc = seg & 65535;
        int n = loc >> 8, k = loc & 255;
        O[loc] = (_Float16)W[k * 256 + n];
    } else if (i < 167936) {
        int loc = i - 163840;
        int j = loc >> 8, k = loc & 255;
        float v = (j < 6) ? Wl3[k * 6 + j] : ((j < 12) ? Wr3[k * 6 + (j - 6)] : 0.0f);
        w3t[loc] = (_Float16)v;
    }
}

// ---------------- MFMA fp16 GEMM pair: A[M x Kp] @ {Wl,Wr}^T + bias -> fp16 ----------------
// 128 rows x 128-col half of BOTH matrices per block (grid y = 2).

#define LDST 40

__global__ __launch_bounds__(256, 2) void k_gemm_pair_mfma(
        const _Float16* __restrict__ A, int M, int Kp,
        const _Float16* __restrict__ Btl, const _Float16* __restrict__ Btr,
        const float* __restrict__ bl, const float* __restrict__ br,
        _Float16* __restrict__ Cl, _Float16* __restrict__ Cr) {
    __shared__ _Float16 As[128 * LDST];
    __shared__ _Float16 Bls[128 * LDST];
    __shared__ _Float16 Brs[128 * LDST];
    const int t = threadIdx.x;
    const int wave = t >> 6, lane = t & 63;
    const int wr = wave >> 1, wc = wave & 1;
    const int l15 = lane & 15, l4 = lane >> 4;
    const int row0 = blockIdx.x * 128;
    const int col0 = blockIdx.y * 128;

    f32x4 accl[4][4], accr[4][4];
    #pragma unroll
    for (int a = 0; a < 4; a++)
        #pragma unroll
        for (int b = 0; b < 4; b++) {
            accl[a][b] = (f32x4){0.f, 0.f, 0.f, 0.f};
            accr[a][b] = (f32x4){0.f, 0.f, 0.f, 0.f};
        }

    for (int k0 = 0; k0 < Kp; k0 += 32) {
        #pragma unroll
        for (int i = 0; i < 2; i++) {
            int s = t + i * 256;
            int r = s >> 2, ks = (s & 3) * 8;
            int gr = row0 + r;
            uint4 va = make_uint4(0u, 0u, 0u, 0u);
            if (gr < M) va = *(const uint4*)&A[(size_t)gr * Kp + k0 + ks];
            *(uint4*)&As[r * LDST + ks] = va;
            *(uint4*)&Bls[r * LDST + ks] = *(const uint4*)&Btl[(size_t)(col0 + r) * Kp + k0 + ks];
            *(uint4*)&Brs[r * LDST + ks] = *(const uint4*)&Btr[(size_t)(col0 + r) * Kp + k0 + ks];
        }
        __syncthreads();
        f16x8 af[4], bfl[4], bfr[4];
        #pragma unroll
        for (int mt = 0; mt < 4; mt++)
            af[mt] = *(const f16x8*)&As[(wr * 64 + mt * 16 + l15) * LDST + l4 * 8];
        #pragma unroll
        for (int nt = 0; nt < 4; nt++) {
            bfl[nt] = *(const f16x8*)&Bls[(wc * 64 + nt * 16 + l15) * LDST + l4 * 8];
            bfr[nt] = *(const f16x8*)&Brs[(wc * 64 + nt * 16 + l15) * LDST + l4 * 8];
        }
        #pragma unroll
        for (int mt = 0; mt < 4; mt++)
            #pragma unroll
            for (int nt = 0; nt < 4; nt++) {
                accl[mt][nt] = __builtin_amdgcn_mfma_f32_16x16x32_f16(
                    af[mt], bfl[nt], accl[mt][nt], 0, 0, 0);
                accr[mt][nt] = __builtin_amdgcn_mfma_f32_16x16x32_f16(
                    af[mt], bfr[nt], accr[mt][nt], 0, 0, 0);
            }
        __syncthreads();
    }
    #pragma unroll
    for (int nt = 0; nt < 4; nt++) {
        int gc = col0 + wc * 64 + nt * 16 + l15;
        float bvl = bl[gc], bvr = br[gc];
        #pragma unroll
        for (int mt = 0; mt < 4; mt++) {
            #pragma unroll
            for (int r = 0; r < 4; r++) {
                int gr = row0 + wr * 64 + mt * 16 + l4 * 4 + r;
                if (gr < M) {
                    Cl[(size_t)gr * 256 + gc] = (_Float16)(accl[mt][nt][r] + bvl);
                    Cr[(size_t)gr * 256 + gc] = (_Float16)(accr[mt][nt][r] + bvr);
                }
            }
        }
    }
}

// ---------------- Layer 3 transform via MFMA ----------------

__global__ __launch_bounds__(256) void k_gemm3_mfma(
        const _Float16* __restrict__ h,
        const _Float16* __restrict__ W3t,
        const float* __restrict__ bl, const float* __restrict__ br,
        _Float16* __restrict__ l3, int N) {
    const int wave = threadIdx.x >> 6, lane = threadIdx.x & 63;
    const int l15 = lane & 15, l4 = lane >> 4;
    const int row0 = blockIdx.x * 64 + wave * 16;
    if (row0 >= N) return;

    f16x8 bfr[8];
    #pragma unroll
    for (int ks = 0; ks < 8; ks++)
        bfr[ks] = *(const f16x8*)&W3t[l15 * 256 + ks * 32 + l4 * 8];

    const int arow = min(row0 + l15, N - 1);
    const size_t abase = (size_t)arow * 256;
    f32x4 acc = (f32x4){0.f, 0.f, 0.f, 0.f};
    #pragma unroll
    for (int ks = 0; ks < 8; ks++) {
        f16x8 af = *(const f16x8*)&h[abase + ks * 32 + l4 * 8];
        acc = __builtin_amdgcn_mfma_f32_16x16x32_f16(af, bfr[ks], acc, 0, 0, 0);
    }
    const float bv = (l15 < 6) ? bl[l15] : ((l15 < 12) ? br[l15 - 6] : 0.0f);
    #pragma unroll
    for (int r = 0; r < 4; r++) {
        int gr = row0 + l4 * 4 + r;
        if (gr < N && l15 < 12)
            l3[(size_t)gr * 16 + l15] = (_Float16)(acc[r] + bv);
    }
}

// ---------------- Aggregation layers 1&2 (H=4, C=64), fp16 tables, online softmax ----------------
// Wave-per-node, n made wave-uniform (readfirstlane) so the edge-index stream
// comes in on the SCALAR pipe (s_load) and gather bases are SGPRs.
// Packed fp16 elementwise (v_pk_*), v_dot2_f32_f16 for the att-dot,
// v_fma_mix_f32 for the p*x accumulate.

__global__ __launch_bounds__(256) void k_agg256(const _Float16* __restrict__ xl,
                                                const _Float16* __restrict__ xr,
                                                const int* __restrict__ row_ptr,
                                                const int* __restrict__ src_sorted,
                                                const float* __restrict__ att,
                                                const float* __restrict__ bias,
                                                _Float16* __restrict__ h_out, int N) {
    const int wave = threadIdx.x >> 6;
    const int lane = threadIdx.x & 63;
    const int n = __builtin_amdgcn_readfirstlane(blockIdx.x * 4 + wave);
    if (n >= N) return;
    const int ci = lane * 4;
    const h4 xr4 = *(const h4*)&xr[(size_t)n * 256 + ci];
    const float4 at4 = *(const float4*)&att[ci];
    const h2 ata = {(_Float16)at4.x, (_Float16)at4.y};
    const h2 atb = {(_Float16)at4.z, (_Float16)at4.w};
    float a0 = 0.f, a1 = 0.f, a2 = 0.f, a3 = 0.f;
    float m = -INFINITY, s = 0.0f;
    const int beg = row_ptr[n], end = row_ptr[n + 1];

    int j = beg;
    // ---- batches of 8, scalar index loads ----
    for (; j + 8 <= end; j += 8) {
        h4 v[8];
        float lg[8];
        #pragma unroll
        for (int e = 0; e < 8; e++) {
            int sv = src_sorted[j + e];               // uniform -> s_load
            v[e] = *(const h4*)&xl[(size_t)sv * 256 + ci];
        }
        #pragma unroll
        for (int e = 0; e < 8; e++) {
            h4 t = v[e] + xr4;
            h4 lk = __builtin_elementwise_max(t, t * (_Float16)NEG_SLOPE);
            h2 lo = __builtin_shufflevector(lk, lk, 0, 1);
            h2 hi = __builtin_shufflevector(lk, lk, 2, 3);
            lg[e] = __builtin_amdgcn_fdot2(lo, ata,
                        __builtin_amdgcn_fdot2(hi, atb, 0.0f, false), false);
        }
        #pragma unroll
        for (int d = 1; d < 16; d <<= 1)
            #pragma unroll
            for (int e = 0; e < 8; e++)
                lg[e] += __shfl_xor(lg[e], d, 64);
        float bm = fmaxf(fmaxf(fmaxf(lg[0], lg[1]), fmaxf(lg[2], lg[3])),
                         fmaxf(fmaxf(lg[4], lg[5]), fmaxf(lg[6], lg[7])));
        float nm = fmaxf(m, bm);
        float sc = __expf(m - nm);
        a0 *= sc; a1 *= sc; a2 *= sc; a3 *= sc;
        float ps = 0.f;
        #pragma unroll
        for (int e = 0; e < 8; e++) {
            float p = __expf(lg[e] - nm);
            ps += p;
            a0 = fmaf(p, (float)v[e].x, a0);
            a1 = fmaf(p, (float)v[e].y, a1);
            a2 = fmaf(p, (float)v[e].z, a2);
            a3 = fmaf(p, (float)v[e].w, a3);
        }
        s = s * sc + ps;
        m = nm;
    }
    // ---- per-edge tail (<=7) ----
    for (; j < end; j++) {
        int sv = src_sorted[j];                       // uniform -> s_load
        h4 v = *(const h4*)&xl[(size_t)sv * 256 + ci];
        h4 t = v + xr4;
        h4 lk = __builtin_elementwise_max(t, t * (_Float16)NEG_SLOPE);
        h2 lo = __builtin_shufflevector(lk, lk, 0, 1);
        h2 hi = __builtin_shufflevector(lk, lk, 2, 3);
        float lg = __builtin_amdgcn_fdot2(lo, ata,
                       __builtin_amdgcn_fdot2(hi, atb, 0.0f, false), false);
        #pragma unroll
        for (int d = 1; d < 16; d <<= 1)
            lg += __shfl_xor(lg, d, 64);
        float nm = fmaxf(m, lg);
        float sc = __expf(m - nm);
        float p  = __expf(lg - nm);
        a0 = fmaf(p, (float)v.x, a0 * sc);
        a1 = fmaf(p, (float)v.y, a1 * sc);
        a2 = fmaf(p, (float)v.z, a2 * sc);
        a3 = fmaf(p, (float)v.w, a3 * sc);
        s = s * sc + p;
        m = nm;
    }
    const float inv = 1.0f / s;
    const float4 bv = *(const float4*)&bias[ci];
    float o0 = a0 * inv + bv.x;
    float o1 = a1 * inv + bv.y;
    float o2 = a2 * inv + bv.z;
    float o3 = a3 * inv + bv.w;
    o0 = o0 > 0.f ? o0 : (__expf(o0) - 1.f);
    o1 = o1 > 0.f ? o1 : (__expf(o1) - 1.f);
    o2 = o2 > 0.f ? o2 : (__expf(o2) - 1.f);
    o3 = o3 > 0.f ? o3 : (__expf(o3) - 1.f);
    h4 hv = {(_Float16)o0, (_Float16)o1, (_Float16)o2, (_Float16)o3};
    *(h4*)&h_out[(size_t)n * 256 + ci] = hv;
}

// ---------------- Layer 3 aggregation (H=6, C=1, mean over heads), packed fp16 l3 ----------------

__global__ __launch_bounds__(64) void k_agg3(const _Float16* __restrict__ l3,
                                             const int* __restrict__ row_ptr,
                                             const int* __restrict__ src_sorted,
                                             const float* __restrict__ att3,
                                             const float* __restrict__ bias3,
                                             float* __restrict__ out, int N) {
    int n = blockIdx.x * 64 + threadIdx.x;
    if (n >= N) return;
    const h4* pn = (const h4*)&l3[(size_t)n * 16];
    h4 q0 = pn[0], q1 = pn[1], q2 = pn[2];
    float xrv[6];
    xrv[0] = (float)q1.z; xrv[1] = (float)q1.w;
    xrv[2] = (float)q2.x; xrv[3] = (float)q2.y;
    xrv[4] = (float)q2.z; xrv[5] = (float)q2.w;
    (void)q0;
    float attv[6], m[6], s[6], acc[6];
    #pragma unroll
    for (int k = 0; k < 6; k++) {
        attv[k] = att3[k];
        m[k] = -INFINITY; s[k] = 0.0f; acc[k] = 0.0f;
    }
    int beg = row_ptr[n], end = row_ptr[n + 1];
    for (int idx = beg; idx < end; idx++) {
        int sv = src_sorted[idx];
        const h4* ps = (const h4*)&l3[(size_t)sv * 16];
        h4 u0 = ps[0], u1 = ps[1];
        float xlv[6];
        xlv[0] = (float)u0.x; xlv[1] = (float)u0.y;
        xlv[2] = (float)u0.z; xlv[3] = (float)u0.w;
        xlv[4] = (float)u1.x; xlv[5] = (float)u1.y;
        #pragma unroll
        for (int k = 0; k < 6; k++) {
            float tt = xlv[k] + xrv[k];
            float lr = fmaxf(tt, NEG_SLOPE * tt);
            float logit = attv[k] * lr;
            float nm = fmaxf(m[k], logit);
            float sc = __expf(m[k] - nm);
            float p  = __expf(logit - nm);
            acc[k] = acc[k] * sc + p * xlv[k];
            s[k]   = s[k] * sc + p;
            m[k]   = nm;
        }
    }
    float o = 0.0f;
    #pragma unroll
    for (int k = 0; k < 6; k++) o += acc[k] / s[k];
    out[n] = o * (1.0f / 6.0f) + bias3[0];
}

// ---------------- launch ----------------

extern "C" void kernel_launch(void* const* d_in, const int* in_sizes, int n_in,
                              void* d_out, int out_size, void* d_ws, size_t ws_size,
                              hipStream_t stream) {
    const float* x    = (const float*)d_in[0];
    const int*   ei   = (const int*)  d_in[1];
    const float* Wl1  = (const float*)d_in[2];
    const float* bl1  = (const float*)d_in[3];
    const float* Wr1  = (const float*)d_in[4];
    const float* br1  = (const float*)d_in[5];
    const float* att1 = (const float*)d_in[6];
    const float* bias1= (const float*)d_in[7];
    const float* Wl2  = (const float*)d_in[8];
    const float* bl2  = (const float*)d_in[9];
    const float* Wr2  = (const float*)d_in[10];
    const float* br2  = (const float*)d_in[11];
    const float* att2 = (const float*)d_in[12];
    const float* bias2= (const float*)d_in[13];
    const float* Wl3  = (const float*)d_in[14];
    const float* bl3  = (const float*)d_in[15];
    const float* Wr3  = (const float*)d_in[16];
    const float* br3  = (const float*)d_in[17];
    const float* att3 = (const float*)d_in[18];
    const float* bias3= (const float*)d_in[19];

    const int F  = in_sizes[2] / 256;   // 58
    const int N  = in_sizes[0] / F;     // 50000
    const int E  = in_sizes[1] / 2;     // 500000
    const int Et = E + N;

    char* ws = (char*)d_ws;
    size_t off = 0;
    auto carve = [&](size_t bytes) -> char* {
        char* p = ws + off;
        off = (off + bytes + 255) & ~(size_t)255;
        return p;
    };
    _Float16* xb   = (_Float16*)carve((size_t)N * 64 * 2);
    _Float16* xlb  = (_Float16*)carve((size_t)N * 256 * 2);
    _Float16* xrb  = (_Float16*)carve((size_t)N * 256 * 2);
    _Float16* hb   = (_Float16*)carve((size_t)N * 256 * 2);
    _Float16* wtl1 = (_Float16*)carve(256 * 64 * 2);
    _Float16* wtr1 = (_Float16*)carve(256 * 64 * 2);
    _Float16* wtl2 = (_Float16*)carve(256 * 256 * 2);
    _Float16* wtr2 = (_Float16*)carve(256 * 256 * 2);
    _Float16* w3t  = (_Float16*)carve(16 * 256 * 2);
    _Float16* l3   = (_Float16*)carve((size_t)N * 16 * 2);
    int* cnt        = (int*)carve((size_t)N * 4);
    int* row_ptr    = (int*)carve((size_t)(N + 1) * 4);
    int* cursor     = (int*)carve((size_t)N * 4);
    int* src_sorted = (int*)carve((size_t)Et * 4);
    int* bsums      = (int*)carve(1024 * 4);

    const int gN  = (N + 255) / 256;
    const int gEt = (Et + 255) / 256;
    const int gW  = (N + 3) / 4;

    // --- CSR build ---
    hipMemsetAsync(cnt, 0, (size_t)N * 4, stream);
    k_count<<<gEt, 256, 0, stream>>>(ei, E, Et, cnt);
    k_scan_block<<<gN, 256, 0, stream>>>(cnt, row_ptr, bsums, N);
    k_scan_bsums<<<1, 256, 0, stream>>>(bsums, gN);
    k_scan_add<<<gN, 256, 0, stream>>>(row_ptr, bsums, cursor, N, Et);
    k_scatter<<<gEt, 256, 0, stream>>>(ei, E, Et, cursor, src_sorted);

    // --- casts / packs ---
    k_cast_x<<<((N << 6) + 255) / 256, 256, 0, stream>>>(x, xb, N, F, 6);
    k_cast_w_all<<<656, 256, 0, stream>>>(Wl1, Wr1, Wl2, Wr2, Wl3, Wr3,
                                          wtl1, wtr1, wtl2, wtr2, w3t, F);

    dim3 gemm_grid((N + 127) / 128, 2);

    // --- Layer 1 ---
    k_gemm_pair_mfma<<<gemm_grid, 256, 0, stream>>>(xb, N, 64, wtl1, wtr1, bl1, br1, xlb, xrb);
    k_agg256<<<gW, 256, 0, stream>>>(xlb, xrb, row_ptr, src_sorted, att1, bias1, hb, N);

    // --- Layer 2 ---
    k_gemm_pair_mfma<<<gemm_grid, 256, 0, stream>>>(hb, N, 256, wtl2, wtr2, bl2, br2, xlb, xrb);
    k_agg256<<<gW, 256, 0, stream>>>(xlb, xrb, row_ptr, src_sorted, att2, bias2, hb, N);

    // --- Layer 3 ---
    k_gemm3_mfma<<<(N + 63) / 64, 256, 0, stream>>>(hb, w3t, bl3, br3, l3, N);
    k_agg3<<<(N + 63) / 64, 64, 0, stream>>>(l3, row_ptr, src_sorted, att3, bias3,
                                             (float*)d_out, N);
}

// Round 7
// 353.900 us; speedup vs baseline: 2.5501x; 1.0487x over previous
//
#include <hip/hip_runtime.h>
#include <math.h>

#define NEG_SLOPE 0.2f
#define LOG2E 1.4426950408889634f

typedef __attribute__((ext_vector_type(2))) _Float16 h2;
typedef __attribute__((ext_vector_type(4))) _Float16 h4;
typedef __attribute__((ext_vector_type(8))) _Float16 f16x8;
typedef __attribute__((ext_vector_type(4))) float f32x4;

// DPP-fused 16-lane row sum: quad_perm xor1, xor2, then row_ror 4, 8.
template<int CTRL>
__device__ __forceinline__ float dpp_add_f32(float x) {
    int y = __builtin_amdgcn_update_dpp(0, __float_as_int(x), CTRL, 0xF, 0xF, true);
    return x + __int_as_float(y);
}
__device__ __forceinline__ float rowsum16(float x) {
    x = dpp_add_f32<0xB1>(x);    // quad_perm [1,0,3,2]  (xor 1)
    x = dpp_add_f32<0x4E>(x);    // quad_perm [2,3,0,1]  (xor 2)
    x = dpp_add_f32<0x124>(x);   // row_ror:4
    x = dpp_add_f32<0x128>(x);   // row_ror:8
    return x;
}

// ---------------- CSR build ----------------

__global__ __launch_bounds__(256) void k_count(const int* __restrict__ ei, int E, int Et,
                                               int* __restrict__ cnt) {
    int e = blockIdx.x * 256 + threadIdx.x;
    if (e < Et) {
        int d = (e < E) ? ei[E + e] : (e - E);
        atomicAdd(&cnt[d], 1);
    }
}

__global__ __launch_bounds__(256) void k_scan_block(const int* __restrict__ cnt,
                                                    int* __restrict__ out,
                                                    int* __restrict__ bsums, int n) {
    __shared__ int tmp[256];
    int t = threadIdx.x;
    int i = blockIdx.x * 256 + t;
    int v = (i < n) ? cnt[i] : 0;
    tmp[t] = v;
    __syncthreads();
    for (int d = 1; d < 256; d <<= 1) {
        int add = (t >= d) ? tmp[t - d] : 0;
        __syncthreads();
        tmp[t] += add;
        __syncthreads();
    }
    if (i < n) out[i] = tmp[t] - v;
    if (t == 255) bsums[blockIdx.x] = tmp[t];
}

__global__ __launch_bounds__(256) void k_scan_bsums(int* bsums, int nb) {
    __shared__ int tmp[256];
    int t = threadIdx.x;
    int v = (t < nb) ? bsums[t] : 0;
    tmp[t] = v;
    __syncthreads();
    for (int d = 1; d < 256; d <<= 1) {
        int add = (t >= d) ? tmp[t - d] : 0;
        __syncthreads();
        tmp[t] += add;
        __syncthreads();
    }
    if (t < nb) bsums[t] = tmp[t] - v;
}

__global__ __launch_bounds__(256) void k_scan_add(int* __restrict__ out,
                                                  const int* __restrict__ bsums,
                                                  int* __restrict__ cursor,
                                                  int n, int total) {
    int i = blockIdx.x * 256 + threadIdx.x;
    if (i < n) {
        int v = out[i] + bsums[blockIdx.x];
        out[i] = v;
        cursor[i] = v;
    }
    if (i == 0) out[n] = total;
}

__global__ __launch_bounds__(256) void k_scatter(const int* __restrict__ ei, int E, int Et,
                                                 int* __restrict__ cursor,
                                                 int* __restrict__ src_sorted) {
    int e = blockIdx.x * 256 + threadIdx.x;
    if (e < Et) {
        int s, d;
        if (e < E) { s = ei[e]; d = ei[E + e]; } else { s = d = e - E; }
        int pos = atomicAdd(&cursor[d], 1);
        src_sorted[pos] = s;
    }
}

// ---------------- casts ----------------

__global__ __launch_bounds__(256) void k_cast_x(const float* __restrict__ x,
                                                _Float16* __restrict__ xb,
                                                int N, int F, int kshift) {
    int i = blockIdx.x * 256 + threadIdx.x;
    if (i < (N << kshift)) {
        int n = i >> kshift, k = i & ((1 << kshift) - 1);
        float v = (k < F) ? x[n * F + k] : 0.0f;
        xb[i] = (_Float16)v;
    }
}

__global__ __launch_bounds__(256) void k_cast_w_all(
        const float* __restrict__ Wl1, const float* __restrict__ Wr1,
        const float* __restrict__ Wl2, const float* __restrict__ Wr2,
        const float* __restrict__ Wl3, const float* __restrict__ Wr3,
        _Float16* __restrict__ wtl1, _Float16* __restrict__ wtr1,
        _Float16* __restrict__ wtl2, _Float16* __restrict__ wtr2,
        _Float16* __restrict__ w3t, int F) {
    int i = blockIdx.x * 256 + threadIdx.x;
    if (i < 32768) {
        const float* W = (i < 16384) ? Wl1 : Wr1;
        _Float16* O = (i < 16384) ? wtl1 : wtr1;
        int loc = i & 16383;
        int n = loc >> 6, k = loc & 63;
        O[loc] = (_Float16)(k < F ? W[k * 256 + n] : 0.0f);
    } else if (i < 163840) {
        int seg = i - 32768;
        const float* W = (seg < 65536) ? Wl2 : Wr2;
        _Float16* O = (seg < 65536) ? wtl2 : wtr2;
        int loc = seg & 65535;
        int n = loc >> 8, k = loc & 255;
        O[loc] = (_Float16)W[k * 256 + n];
    } else if (i < 167936) {
        int loc = i - 163840;
        int j = loc >> 8, k = loc & 255;
        float v = (j < 6) ? Wl3[k * 6 + j] : ((j < 12) ? Wr3[k * 6 + (j - 6)] : 0.0f);
        w3t[loc] = (_Float16)v;
    }
}

// ---------------- MFMA fp16 GEMM pair ----------------

#define LDST 40

__global__ __launch_bounds__(256, 2) void k_gemm_pair_mfma(
        const _Float16* __restrict__ A, int M, int Kp,
        const _Float16* __restrict__ Btl, const _Float16* __restrict__ Btr,
        const float* __restrict__ bl, const float* __restrict__ br,
        _Float16* __restrict__ Cl, _Float16* __restrict__ Cr) {
    __shared__ _Float16 As[128 * LDST];
    __shared__ _Float16 Bls[128 * LDST];
    __shared__ _Float16 Brs[128 * LDST];
    const int t = threadIdx.x;
    const int wave = t >> 6, lane = t & 63;
    const int wr = wave >> 1, wc = wave & 1;
    const int l15 = lane & 15, l4 = lane >> 4;
    const int row0 = blockIdx.x * 128;
    const int col0 = blockIdx.y * 128;

    f32x4 accl[4][4], accr[4][4];
    #pragma unroll
    for (int a = 0; a < 4; a++)
        #pragma unroll
        for (int b = 0; b < 4; b++) {
            accl[a][b] = (f32x4){0.f, 0.f, 0.f, 0.f};
            accr[a][b] = (f32x4){0.f, 0.f, 0.f, 0.f};
        }

    for (int k0 = 0; k0 < Kp; k0 += 32) {
        #pragma unroll
        for (int i = 0; i < 2; i++) {
            int s = t + i * 256;
            int r = s >> 2, ks = (s & 3) * 8;
            int gr = row0 + r;
            uint4 va = make_uint4(0u, 0u, 0u, 0u);
            if (gr < M) va = *(const uint4*)&A[(size_t)gr * Kp + k0 + ks];
            *(uint4*)&As[r * LDST + ks] = va;
            *(uint4*)&Bls[r * LDST + ks] = *(const uint4*)&Btl[(size_t)(col0 + r) * Kp + k0 + ks];
            *(uint4*)&Brs[r * LDST + ks] = *(const uint4*)&Btr[(size_t)(col0 + r) * Kp + k0 + ks];
        }
        __syncthreads();
        f16x8 af[4], bfl[4], bfr[4];
        #pragma unroll
        for (int mt = 0; mt < 4; mt++)
            af[mt] = *(const f16x8*)&As[(wr * 64 + mt * 16 + l15) * LDST + l4 * 8];
        #pragma unroll
        for (int nt = 0; nt < 4; nt++) {
            bfl[nt] = *(const f16x8*)&Bls[(wc * 64 + nt * 16 + l15) * LDST + l4 * 8];
            bfr[nt] = *(const f16x8*)&Brs[(wc * 64 + nt * 16 + l15) * LDST + l4 * 8];
        }
        #pragma unroll
        for (int mt = 0; mt < 4; mt++)
            #pragma unroll
            for (int nt = 0; nt < 4; nt++) {
                accl[mt][nt] = __builtin_amdgcn_mfma_f32_16x16x32_f16(
                    af[mt], bfl[nt], accl[mt][nt], 0, 0, 0);
                accr[mt][nt] = __builtin_amdgcn_mfma_f32_16x16x32_f16(
                    af[mt], bfr[nt], accr[mt][nt], 0, 0, 0);
            }
        __syncthreads();
    }
    #pragma unroll
    for (int nt = 0; nt < 4; nt++) {
        int gc = col0 + wc * 64 + nt * 16 + l15;
        float bvl = bl[gc], bvr = br[gc];
        #pragma unroll
        for (int mt = 0; mt < 4; mt++) {
            #pragma unroll
            for (int r = 0; r < 4; r++) {
                int gr = row0 + wr * 64 + mt * 16 + l4 * 4 + r;
                if (gr < M) {
                    Cl[(size_t)gr * 256 + gc] = (_Float16)(accl[mt][nt][r] + bvl);
                    Cr[(size_t)gr * 256 + gc] = (_Float16)(accr[mt][nt][r] + bvr);
                }
            }
        }
    }
}

// ---------------- Layer 3 transform via MFMA ----------------

__global__ __launch_bounds__(256) void k_gemm3_mfma(
        const _Float16* __restrict__ h,
        const _Float16* __restrict__ W3t,
        const float* __restrict__ bl, const float* __restrict__ br,
        _Float16* __restrict__ l3, int N) {
    const int wave = threadIdx.x >> 6, lane = threadIdx.x & 63;
    const int l15 = lane & 15, l4 = lane >> 4;
    const int row0 = blockIdx.x * 64 + wave * 16;
    if (row0 >= N) return;

    f16x8 bfr[8];
    #pragma unroll
    for (int ks = 0; ks < 8; ks++)
        bfr[ks] = *(const f16x8*)&W3t[l15 * 256 + ks * 32 + l4 * 8];

    const int arow = min(row0 + l15, N - 1);
    const size_t abase = (size_t)arow * 256;
    f32x4 acc = (f32x4){0.f, 0.f, 0.f, 0.f};
    #pragma unroll
    for (int ks = 0; ks < 8; ks++) {
        f16x8 af = *(const f16x8*)&h[abase + ks * 32 + l4 * 8];
        acc = __builtin_amdgcn_mfma_f32_16x16x32_f16(af, bfr[ks], acc, 0, 0, 0);
    }
    const float bv = (l15 < 6) ? bl[l15] : ((l15 < 12) ? br[l15 - 6] : 0.0f);
    #pragma unroll
    for (int r = 0; r < 4; r++) {
        int gr = row0 + l4 * 4 + r;
        if (gr < N && l15 < 12)
            l3[(size_t)gr * 16 + l15] = (_Float16)(acc[r] + bv);
    }
}

// ---------------- Aggregation layers 1&2 (H=4, C=64), fp16, online softmax ----------------
// Wave-per-node (n wave-uniform -> scalar index stream). DPP 16-lane reduce,
// base-2 softmax (log2e folded into att), 2-stage gather prefetch.

__global__ __launch_bounds__(256) void k_agg256(const _Float16* __restrict__ xl,
                                                const _Float16* __restrict__ xr,
                                                const int* __restrict__ row_ptr,
                                                const int* __restrict__ src_sorted,
                                                const float* __restrict__ att,
                                                const float* __restrict__ bias,
                                                _Float16* __restrict__ h_out, int N) {
    const int wave = threadIdx.x >> 6;
    const int lane = threadIdx.x & 63;
    const int n = __builtin_amdgcn_readfirstlane(blockIdx.x * 4 + wave);
    if (n >= N) return;
    const int ci = lane * 4;
    const h4 xr4 = *(const h4*)&xr[(size_t)n * 256 + ci];
    const float4 at4 = *(const float4*)&att[ci];
    // fold log2e into att: logits live in base-2 domain (alpha invariant)
    const h2 ata = {(_Float16)(at4.x * LOG2E), (_Float16)(at4.y * LOG2E)};
    const h2 atb = {(_Float16)(at4.z * LOG2E), (_Float16)(at4.w * LOG2E)};
    float a0 = 0.f, a1 = 0.f, a2 = 0.f, a3 = 0.f;
    float m = -INFINITY, s = 0.0f;
    const int beg = row_ptr[n], end = row_ptr[n + 1];

    int j = beg;
    h4 v[8], vn[8];
    bool has = (j + 8 <= end);
    if (has) {
        #pragma unroll
        for (int e = 0; e < 8; e++) {
            int sv = src_sorted[j + e];               // uniform -> s_load
            v[e] = *(const h4*)&xl[(size_t)sv * 256 + ci];
        }
    }
    while (has) {
        const int jn = j + 8;
        const bool hasN = (jn + 8 <= end);
        if (hasN) {
            #pragma unroll
            for (int e = 0; e < 8; e++) {
                int sv = src_sorted[jn + e];
                vn[e] = *(const h4*)&xl[(size_t)sv * 256 + ci];
            }
        }
        float lg[8];
        #pragma unroll
        for (int e = 0; e < 8; e++) {
            h4 t = v[e] + xr4;
            h4 lk = __builtin_elementwise_max(t, t * (_Float16)NEG_SLOPE);
            h2 lo = __builtin_shufflevector(lk, lk, 0, 1);
            h2 hi = __builtin_shufflevector(lk, lk, 2, 3);
            lg[e] = __builtin_amdgcn_fdot2(lo, ata,
                        __builtin_amdgcn_fdot2(hi, atb, 0.0f, false), false);
        }
        #pragma unroll
        for (int e = 0; e < 8; e++) lg[e] = rowsum16(lg[e]);
        float bm = fmaxf(fmaxf(fmaxf(lg[0], lg[1]), fmaxf(lg[2], lg[3])),
                         fmaxf(fmaxf(lg[4], lg[5]), fmaxf(lg[6], lg[7])));
        float nm = fmaxf(m, bm);
        float sc = __builtin_amdgcn_exp2f(m - nm);
        a0 *= sc; a1 *= sc; a2 *= sc; a3 *= sc;
        float ps = 0.f;
        #pragma unroll
        for (int e = 0; e < 8; e++) {
            float p = __builtin_amdgcn_exp2f(lg[e] - nm);
            ps += p;
            a0 = fmaf(p, (float)v[e].x, a0);
            a1 = fmaf(p, (float)v[e].y, a1);
            a2 = fmaf(p, (float)v[e].z, a2);
            a3 = fmaf(p, (float)v[e].w, a3);
        }
        s = s * sc + ps;
        m = nm;
        if (hasN) {
            #pragma unroll
            for (int e = 0; e < 8; e++) v[e] = vn[e];
        }
        j = jn;
        has = hasN;
    }
    // per-edge tail (<=7)
    for (; j < end; j++) {
        int sv = src_sorted[j];
        h4 vv = *(const h4*)&xl[(size_t)sv * 256 + ci];
        h4 t = vv + xr4;
        h4 lk = __builtin_elementwise_max(t, t * (_Float16)NEG_SLOPE);
        h2 lo = __builtin_shufflevector(lk, lk, 0, 1);
        h2 hi = __builtin_shufflevector(lk, lk, 2, 3);
        float lg = __builtin_amdgcn_fdot2(lo, ata,
                       __builtin_amdgcn_fdot2(hi, atb, 0.0f, false), false);
        lg = rowsum16(lg);
        float nm = fmaxf(m, lg);
        float sc = __builtin_amdgcn_exp2f(m - nm);
        float p  = __builtin_amdgcn_exp2f(lg - nm);
        a0 = fmaf(p, (float)vv.x, a0 * sc);
        a1 = fmaf(p, (float)vv.y, a1 * sc);
        a2 = fmaf(p, (float)vv.z, a2 * sc);
        a3 = fmaf(p, (float)vv.w, a3 * sc);
        s = s * sc + p;
        m = nm;
    }
    const float inv = 1.0f / s;
    const float4 bv = *(const float4*)&bias[ci];
    float o0 = a0 * inv + bv.x;
    float o1 = a1 * inv + bv.y;
    float o2 = a2 * inv + bv.z;
    float o3 = a3 * inv + bv.w;
    o0 = o0 > 0.f ? o0 : (__expf(o0) - 1.f);
    o1 = o1 > 0.f ? o1 : (__expf(o1) - 1.f);
    o2 = o2 > 0.f ? o2 : (__expf(o2) - 1.f);
    o3 = o3 > 0.f ? o3 : (__expf(o3) - 1.f);
    h4 hv = {(_Float16)o0, (_Float16)o1, (_Float16)o2, (_Float16)o3};
    *(h4*)&h_out[(size_t)n * 256 + ci] = hv;
}

// ---------------- Layer 3 aggregation (H=6, C=1, mean over heads) ----------------

__global__ __launch_bounds__(64) void k_agg3(const _Float16* __restrict__ l3,
                                             const int* __restrict__ row_ptr,
                                             const int* __restrict__ src_sorted,
                                             const float* __restrict__ att3,
                                             const float* __restrict__ bias3,
                                             float* __restrict__ out, int N) {
    int n = blockIdx.x * 64 + threadIdx.x;
    if (n >= N) return;
    const h4* pn = (const h4*)&l3[(size_t)n * 16];
    h4 q1 = pn[1], q2 = pn[2];
    float xrv[6];
    xrv[0] = (float)q1.z; xrv[1] = (float)q1.w;
    xrv[2] = (float)q2.x; xrv[3] = (float)q2.y;
    xrv[4] = (float)q2.z; xrv[5] = (float)q2.w;
    float attv[6], m[6], s[6], acc[6];
    #pragma unroll
    for (int k = 0; k < 6; k++) {
        attv[k] = att3[k] * LOG2E;
        m[k] = -INFINITY; s[k] = 0.0f; acc[k] = 0.0f;
    }
    int beg = row_ptr[n], end = row_ptr[n + 1];
    for (int idx = beg; idx < end; idx++) {
        int sv = src_sorted[idx];
        const h4* ps = (const h4*)&l3[(size_t)sv * 16];
        h4 u0 = ps[0], u1 = ps[1];
        float xlv[6];
        xlv[0] = (float)u0.x; xlv[1] = (float)u0.y;
        xlv[2] = (float)u0.z; xlv[3] = (float)u0.w;
        xlv[4] = (float)u1.x; xlv[5] = (float)u1.y;
        #pragma unroll
        for (int k = 0; k < 6; k++) {
            float tt = xlv[k] + xrv[k];
            float lr = fmaxf(tt, NEG_SLOPE * tt);
            float logit = attv[k] * lr;
            float nm = fmaxf(m[k], logit);
            float sc = __builtin_amdgcn_exp2f(m[k] - nm);
            float p  = __builtin_amdgcn_exp2f(logit - nm);
            acc[k] = acc[k] * sc + p * xlv[k];
            s[k]   = s[k] * sc + p;
            m[k]   = nm;
        }
    }
    float o = 0.0f;
    #pragma unroll
    for (int k = 0; k < 6; k++) o += acc[k] / s[k];
    out[n] = o * (1.0f / 6.0f) + bias3[0];
}

// ---------------- launch ----------------

extern "C" void kernel_launch(void* const* d_in, const int* in_sizes, int n_in,
                              void* d_out, int out_size, void* d_ws, size_t ws_size,
                              hipStream_t stream) {
    const float* x    = (const float*)d_in[0];
    const int*   ei   = (const int*)  d_in[1];
    const float* Wl1  = (const float*)d_in[2];
    const float* bl1  = (const float*)d_in[3];
    const float* Wr1  = (const float*)d_in[4];
    const float* br1  = (const float*)d_in[5];
    const float* att1 = (const float*)d_in[6];
    const float* bias1= (const float*)d_in[7];
    const float* Wl2  = (const float*)d_in[8];
    const float* bl2  = (const float*)d_in[9];
    const float* Wr2  = (const float*)d_in[10];
    const float* br2  = (const float*)d_in[11];
    const float* att2 = (const float*)d_in[12];
    const float* bias2= (const float*)d_in[13];
    const float* Wl3  = (const float*)d_in[14];
    const float* bl3  = (const float*)d_in[15];
    const float* Wr3  = (const float*)d_in[16];
    const float* br3  = (const float*)d_in[17];
    const float* att3 = (const float*)d_in[18];
    const float* bias3= (const float*)d_in[19];

    const int F  = in_sizes[2] / 256;   // 58
    const int N  = in_sizes[0] / F;     // 50000
    const int E  = in_sizes[1] / 2;     // 500000
    const int Et = E + N;

    char* ws = (char*)d_ws;
    size_t off = 0;
    auto carve = [&](size_t bytes) -> char* {
        char* p = ws + off;
        off = (off + bytes + 255) & ~(size_t)255;
        return p;
    };
    _Float16* xb   = (_Float16*)carve((size_t)N * 64 * 2);
    _Float16* xlb  = (_Float16*)carve((size_t)N * 256 * 2);
    _Float16* xrb  = (_Float16*)carve((size_t)N * 256 * 2);
    _Float16* hb   = (_Float16*)carve((size_t)N * 256 * 2);
    _Float16* wtl1 = (_Float16*)carve(256 * 64 * 2);
    _Float16* wtr1 = (_Float16*)carve(256 * 64 * 2);
    _Float16* wtl2 = (_Float16*)carve(256 * 256 * 2);
    _Float16* wtr2 = (_Float16*)carve(256 * 256 * 2);
    _Float16* w3t  = (_Float16*)carve(16 * 256 * 2);
    _Float16* l3   = (_Float16*)carve((size_t)N * 16 * 2);
    int* cnt        = (int*)carve((size_t)N * 4);
    int* row_ptr    = (int*)carve((size_t)(N + 1) * 4);
    int* cursor     = (int*)carve((size_t)N * 4);
    int* src_sorted = (int*)carve((size_t)Et * 4);
    int* bsums      = (int*)carve(1024 * 4);

    const int gN  = (N + 255) / 256;
    const int gEt = (Et + 255) / 256;
    const int gW  = (N + 3) / 4;

    // --- CSR build ---
    hipMemsetAsync(cnt, 0, (size_t)N * 4, stream);
    k_count<<<gEt, 256, 0, stream>>>(ei, E, Et, cnt);
    k_scan_block<<<gN, 256, 0, stream>>>(cnt, row_ptr, bsums, N);
    k_scan_bsums<<<1, 256, 0, stream>>>(bsums, gN);
    k_scan_add<<<gN, 256, 0, stream>>>(row_ptr, bsums, cursor, N, Et);
    k_scatter<<<gEt, 256, 0, stream>>>(ei, E, Et, cursor, src_sorted);

    // --- casts / packs ---
    k_cast_x<<<((N << 6) + 255) / 256, 256, 0, stream>>>(x, xb, N, F, 6);
    k_cast_w_all<<<656, 256, 0, stream>>>(Wl1, Wr1, Wl2, Wr2, Wl3, Wr3,
                                          wtl1, wtr1, wtl2, wtr2, w3t, F);

    dim3 gemm_grid((N + 127) / 128, 2);

    // --- Layer 1 ---
    k_gemm_pair_mfma<<<gemm_grid, 256, 0, stream>>>(xb, N, 64, wtl1, wtr1, bl1, br1, xlb, xrb);
    k_agg256<<<gW, 256, 0, stream>>>(xlb, xrb, row_ptr, src_sorted, att1, bias1, hb, N);

    // --- Layer 2 ---
    k_gemm_pair_mfma<<<gemm_grid, 256, 0, stream>>>(hb, N, 256, wtl2, wtr2, bl2, br2, xlb, xrb);
    k_agg256<<<gW, 256, 0, stream>>>(xlb, xrb, row_ptr, src_sorted, att2, bias2, hb, N);

    // --- Layer 3 ---
    k_gemm3_mfma<<<(N + 63) / 64, 256, 0, stream>>>(hb, w3t, bl3, br3, l3, N);
    k_agg3<<<(N + 63) / 64, 64, 0, stream>>>(l3, row_ptr, src_sorted, att3, bias3,
                                             (float*)d_out, N);
}